// Round 1
// baseline (3214.398 us; speedup 1.0000x reference)
//
#include <hip/hip_runtime.h>
#include <math.h>

#define NN   50000
#define NE   800000
#define HID  128
#define NRBF 32
#define DIN  417   // 3*HID + NRBF + 1

constexpr int TILE_E = 64;
constexpr int TILE_N = 64;

__device__ __forceinline__ float silu_f(float x) {
  return x / (1.0f + __expf(-x));
}

__global__ void zero_kernel(float* __restrict__ p, int n) {
  int i = blockIdx.x * blockDim.x + threadIdx.x;
  const int stride = gridDim.x * blockDim.x;
  for (; i < n; i += stride) p[i] = 0.0f;
}

__global__ void counts_kernel(const int* __restrict__ edge_index, float* __restrict__ counts) {
  const int e = blockIdx.x * blockDim.x + threadIdx.x;
  if (e < NE) atomicAdd(&counts[edge_index[NE + e]], 1.0f);
}

// 64 edges per block: stage m_in rows in LDS, 2-layer MLP, atomic scatter into sums.
__global__ __launch_bounds__(256, 1)
void edge_kernel(const float* __restrict__ h, const float* __restrict__ pos,
                 const int* __restrict__ edge_index, const int* __restrict__ edge_type,
                 const float* __restrict__ emb,
                 const float* __restrict__ mw1, const float* __restrict__ mb1,
                 const float* __restrict__ mw2, const float* __restrict__ mb2,
                 float* __restrict__ sums)
{
  __shared__ float sA[TILE_E * DIN];    // 106.75 KB: m_in rows
  __shared__ float sX[TILE_E * HID];    // 32 KB: layer-1 activations
  __shared__ int   sSrc[TILE_E];
  __shared__ int   sDst[TILE_E];
  __shared__ int   sEt[TILE_E];
  __shared__ float sDist[TILE_E];

  const int t  = threadIdx.x;
  const int e0 = blockIdx.x * TILE_E;

  if (t < TILE_E) {
    const int e = e0 + t;
    const int s = edge_index[e];
    const int d = edge_index[NE + e];
    sSrc[t] = s; sDst[t] = d; sEt[t] = edge_type[e];
    const float dx = pos[3*s]   - pos[3*d];
    const float dy = pos[3*s+1] - pos[3*d+1];
    const float dz = pos[3*s+2] - pos[3*d+2];
    const float dist = sqrtf(dx*dx + dy*dy + dz*dz);
    sDist[t] = dist;
    sA[t*DIN + 3*HID + NRBF] = dist;   // m_in[416] = dist
  }
  __syncthreads();

  // gather h[src], h[dst], emb[edge_type]
  for (int idx = t; idx < TILE_E*HID; idx += 256) {
    const int e = idx >> 7, c = idx & (HID-1);
    sA[e*DIN + c]         = h[(long)sSrc[e]*HID + c];
    sA[e*DIN + HID + c]   = h[(long)sDst[e]*HID + c];
    sA[e*DIN + 2*HID + c] = emb[sEt[e]*HID + c];
  }
  // radial RBF
  const float step  = 6.0f / 31.0f;
  const float gamma = 1.0f / (step*step);
  for (int idx = t; idx < TILE_E*NRBF; idx += 256) {
    const int e = idx >> 5, r = idx & (NRBF-1);
    const float dd = sDist[e] - step * (float)r;
    sA[e*DIN + 3*HID + r] = __expf(-gamma*dd*dd);
  }
  __syncthreads();

  const int tx = t & 31;   // 32 col-groups of 4 cols
  const int ty = t >> 5;   // 8 edge-groups of 8 edges

  // ---- layer 1: [64 x 417] @ [417 x 128] ----
  const float* wp = mw1 + tx*4;
  float4 acc[8];
  #pragma unroll
  for (int i = 0; i < 8; ++i) acc[i] = make_float4(0.f,0.f,0.f,0.f);

  for (int k = 0; k < DIN; ++k) {
    const float4 w = *reinterpret_cast<const float4*>(wp + (long)k*HID);
    #pragma unroll
    for (int i = 0; i < 8; ++i) {
      const float a = sA[(ty*8+i)*DIN + k];
      acc[i].x = fmaf(a, w.x, acc[i].x);
      acc[i].y = fmaf(a, w.y, acc[i].y);
      acc[i].z = fmaf(a, w.z, acc[i].z);
      acc[i].w = fmaf(a, w.w, acc[i].w);
    }
  }

  const float4 b1 = *reinterpret_cast<const float4*>(mb1 + tx*4);
  #pragma unroll
  for (int i = 0; i < 8; ++i) {
    const int e = ty*8 + i;
    float4 v = acc[i];
    v.x = silu_f(v.x + b1.x); v.y = silu_f(v.y + b1.y);
    v.z = silu_f(v.z + b1.z); v.w = silu_f(v.w + b1.w);
    *reinterpret_cast<float4*>(&sX[e*HID + tx*4]) = v;
  }
  __syncthreads();

  // ---- layer 2: [64 x 128] @ [128 x 128] ----
  const float* wp2 = mw2 + tx*4;
  float4 acc2[8];
  #pragma unroll
  for (int i = 0; i < 8; ++i) acc2[i] = make_float4(0.f,0.f,0.f,0.f);

  for (int k = 0; k < HID; ++k) {
    const float4 w = *reinterpret_cast<const float4*>(wp2 + (long)k*HID);
    #pragma unroll
    for (int i = 0; i < 8; ++i) {
      const float a = sX[(ty*8+i)*HID + k];
      acc2[i].x = fmaf(a, w.x, acc2[i].x);
      acc2[i].y = fmaf(a, w.y, acc2[i].y);
      acc2[i].z = fmaf(a, w.z, acc2[i].z);
      acc2[i].w = fmaf(a, w.w, acc2[i].w);
    }
  }

  const float4 b2 = *reinterpret_cast<const float4*>(mb2 + tx*4);
  #pragma unroll
  for (int i = 0; i < 8; ++i) {
    const int e = ty*8 + i;
    float4 v = acc2[i];
    v.x = silu_f(v.x + b2.x); v.y = silu_f(v.y + b2.y);
    v.z = silu_f(v.z + b2.z); v.w = silu_f(v.w + b2.w);
    float* p = sums + (long)sDst[e]*HID + tx*4;
    atomicAdd(p+0, v.x);
    atomicAdd(p+1, v.y);
    atomicAdd(p+2, v.z);
    atomicAdd(p+3, v.w);
  }
}

// 64 nodes per block: node MLP + residual + LayerNorm + ligand mask.
__global__ __launch_bounds__(256, 1)
void node_kernel(const float* __restrict__ h,
                 const float* __restrict__ sums, const float* __restrict__ counts,
                 const int* __restrict__ node_type,
                 const float* __restrict__ uw1, const float* __restrict__ ub1,
                 const float* __restrict__ uw2, const float* __restrict__ ub2,
                 const float* __restrict__ ln_g, const float* __restrict__ ln_b,
                 float* __restrict__ out)
{
  __shared__ float sIn[TILE_N * 256];   // 64 KB: [h, agg]
  __shared__ float sU[TILE_N * HID];    // 32 KB: layer-1 act, then x = h+update
  __shared__ float sMu[TILE_N];
  __shared__ float sRs[TILE_N];

  const int t  = threadIdx.x;
  const int n0 = blockIdx.x * TILE_N;

  for (int idx = t; idx < TILE_N*HID; idx += 256) {
    const int n = idx >> 7, c = idx & (HID-1);
    const int node = n0 + n;
    float hv = 0.f, av = 0.f;
    if (node < NN) {
      hv = h[(long)node*HID + c];
      av = sums[(long)node*HID + c] / fmaxf(counts[node], 1.0f);
    }
    sIn[n*256 + c]       = hv;
    sIn[n*256 + HID + c] = av;
  }
  __syncthreads();

  const int tx = t & 31;
  const int ty = t >> 5;

  // ---- layer 1: [64 x 256] @ [256 x 128] ----
  const float* wp = uw1 + tx*4;
  float4 acc[8];
  #pragma unroll
  for (int i = 0; i < 8; ++i) acc[i] = make_float4(0.f,0.f,0.f,0.f);
  for (int k = 0; k < 2*HID; ++k) {
    const float4 w = *reinterpret_cast<const float4*>(wp + (long)k*HID);
    #pragma unroll
    for (int i = 0; i < 8; ++i) {
      const float a = sIn[(ty*8+i)*256 + k];
      acc[i].x = fmaf(a, w.x, acc[i].x);
      acc[i].y = fmaf(a, w.y, acc[i].y);
      acc[i].z = fmaf(a, w.z, acc[i].z);
      acc[i].w = fmaf(a, w.w, acc[i].w);
    }
  }
  const float4 b1 = *reinterpret_cast<const float4*>(ub1 + tx*4);
  #pragma unroll
  for (int i = 0; i < 8; ++i) {
    const int e = ty*8 + i;
    float4 v = acc[i];
    v.x = silu_f(v.x + b1.x); v.y = silu_f(v.y + b1.y);
    v.z = silu_f(v.z + b1.z); v.w = silu_f(v.w + b1.w);
    *reinterpret_cast<float4*>(&sU[e*HID + tx*4]) = v;
  }
  __syncthreads();

  // ---- layer 2: [64 x 128] @ [128 x 128] (no activation) ----
  const float* wp2 = uw2 + tx*4;
  float4 acc2[8];
  #pragma unroll
  for (int i = 0; i < 8; ++i) acc2[i] = make_float4(0.f,0.f,0.f,0.f);
  for (int k = 0; k < HID; ++k) {
    const float4 w = *reinterpret_cast<const float4*>(wp2 + (long)k*HID);
    #pragma unroll
    for (int i = 0; i < 8; ++i) {
      const float a = sU[(ty*8+i)*HID + k];
      acc2[i].x = fmaf(a, w.x, acc2[i].x);
      acc2[i].y = fmaf(a, w.y, acc2[i].y);
      acc2[i].z = fmaf(a, w.z, acc2[i].z);
      acc2[i].w = fmaf(a, w.w, acc2[i].w);
    }
  }
  __syncthreads();   // everyone done reading sU

  const float4 b2 = *reinterpret_cast<const float4*>(ub2 + tx*4);
  #pragma unroll
  for (int i = 0; i < 8; ++i) {
    const int e = ty*8 + i;
    float4 v = acc2[i];
    // x = h + update
    v.x = sIn[e*256 + tx*4+0] + v.x + b2.x;
    v.y = sIn[e*256 + tx*4+1] + v.y + b2.y;
    v.z = sIn[e*256 + tx*4+2] + v.z + b2.z;
    v.w = sIn[e*256 + tx*4+3] + v.w + b2.w;
    *reinterpret_cast<float4*>(&sU[e*HID + tx*4]) = v;
  }
  __syncthreads();

  // LayerNorm stats: 4 lanes per node, 32 elems each
  {
    const int n = t >> 2, q = t & 3;
    float sm = 0.f, sq = 0.f;
    #pragma unroll 8
    for (int i = 0; i < 32; ++i) {
      const float v = sU[n*HID + q*32 + i];
      sm += v; sq += v*v;
    }
    sm += __shfl_xor(sm, 1); sq += __shfl_xor(sq, 1);
    sm += __shfl_xor(sm, 2); sq += __shfl_xor(sq, 2);
    const float mu  = sm * (1.0f/HID);
    float var = sq * (1.0f/HID) - mu*mu;
    var = fmaxf(var, 0.0f);
    if (q == 0) { sMu[n] = mu; sRs[n] = rsqrtf(var + 1e-5f); }
  }
  __syncthreads();

  for (int idx = t; idx < TILE_N*HID; idx += 256) {
    const int n = idx >> 7, c = idx & (HID-1);
    const int node = n0 + n;
    if (node >= NN) continue;
    const float xv = sU[n*HID + c];
    const float normed = (xv - sMu[n]) * sRs[n] * ln_g[c] + ln_b[c];
    const float hv = sIn[n*256 + c];
    out[(long)node*HID + c] = (node_type[node] == 0) ? normed : hv;
  }
}

extern "C" void kernel_launch(void* const* d_in, const int* in_sizes, int n_in,
                              void* d_out, int out_size, void* d_ws, size_t ws_size,
                              hipStream_t stream)
{
  const float* h    = (const float*)d_in[0];
  const float* pos  = (const float*)d_in[1];
  const int*   eidx = (const int*)  d_in[2];
  const int*   etyp = (const int*)  d_in[3];
  const int*   ntyp = (const int*)  d_in[4];
  const float* emb  = (const float*)d_in[5];
  const float* mw1  = (const float*)d_in[6];
  const float* mb1  = (const float*)d_in[7];
  const float* mw2  = (const float*)d_in[8];
  const float* mb2  = (const float*)d_in[9];
  const float* uw1  = (const float*)d_in[10];
  const float* ub1  = (const float*)d_in[11];
  const float* uw2  = (const float*)d_in[12];
  const float* ub2  = (const float*)d_in[13];
  const float* lng  = (const float*)d_in[14];
  const float* lnb  = (const float*)d_in[15];

  float* sums   = (float*)d_ws;             // [NN, HID]
  float* counts = sums + (long)NN*HID;      // [NN]

  zero_kernel<<<2048, 256, 0, stream>>>(sums, NN*HID + NN);
  counts_kernel<<<(NE + 255)/256, 256, 0, stream>>>(eidx, counts);
  edge_kernel<<<NE/TILE_E, 256, 0, stream>>>(h, pos, eidx, etyp, emb,
                                             mw1, mb1, mw2, mb2, sums);
  node_kernel<<<(NN + TILE_N - 1)/TILE_N, 256, 0, stream>>>(h, sums, counts, ntyp,
                                                            uw1, ub1, uw2, ub2,
                                                            lng, lnb, (float*)d_out);
}

// Round 2
// 684.554 us; speedup vs baseline: 4.6956x; 4.6956x over previous
//
#include <hip/hip_runtime.h>
#include <hip/hip_bf16.h>
#include <math.h>

#define NN   50000
#define NE   800000
#define HID  128
#define NRBF 32
#define DIN  417          // 3*HID + NRBF + 1
#define KP   448          // DIN padded to 14 k-steps of 32
#define NKS1 14           // k-steps GEMM1
#define NKS2 4            // k-steps GEMM2

typedef __attribute__((ext_vector_type(8))) short short8;   // 8 bf16 (4 VGPRs)
typedef __attribute__((ext_vector_type(4))) float floatx4;  // MFMA acc

constexpr int TILE_E = 64;
constexpr int TILE_N = 64;

__device__ __forceinline__ float silu_f(float x) {
  return x / (1.0f + __expf(-x));
}

__device__ __forceinline__ ushort f2bf(float f) {
  __hip_bfloat16 b = __float2bfloat16(f);
  return *reinterpret_cast<ushort*>(&b);
}

__global__ void zero_kernel(float* __restrict__ p, int n) {
  int i = blockIdx.x * blockDim.x + threadIdx.x;
  const int stride = gridDim.x * blockDim.x;
  for (; i < n; i += stride) p[i] = 0.0f;
}

__global__ void counts_kernel(const int* __restrict__ edge_index, float* __restrict__ counts) {
  const int e = blockIdx.x * blockDim.x + threadIdx.x;
  if (e < NE) atomicAdd(&counts[edge_index[NE + e]], 1.0f);
}

// h [NN,HID] f32 -> bf16
__global__ void convert_h_kernel(const float* __restrict__ h, ushort* __restrict__ hb) {
  const int tid = blockIdx.x * blockDim.x + threadIdx.x;
  if (tid >= NN * HID / 8) return;
  const float4 f0 = reinterpret_cast<const float4*>(h)[tid * 2];
  const float4 f1 = reinterpret_cast<const float4*>(h)[tid * 2 + 1];
  union { ushort u[8]; uint4 v; } o;
  o.u[0] = f2bf(f0.x); o.u[1] = f2bf(f0.y); o.u[2] = f2bf(f0.z); o.u[3] = f2bf(f0.w);
  o.u[4] = f2bf(f1.x); o.u[5] = f2bf(f1.y); o.u[6] = f2bf(f1.z); o.u[7] = f2bf(f1.w);
  reinterpret_cast<uint4*>(hb)[tid] = o.v;
}

// Pack W [Korig x 128] f32 into bf16 MFMA B-fragment order:
// out[((kk*8 + c)*64 + lane)*8 + j] = W[kk*32 + (lane>>4)*8 + j][c*16 + (lane&15)]
// (zero-padded for k >= Korig). A-frags use the SAME k-slot convention, so the
// contraction is invariant to the HW's exact K permutation.
__global__ void pack_w_kernel(const float* __restrict__ W, ushort* __restrict__ out,
                              int Korig, int nks) {
  const int tid = blockIdx.x * blockDim.x + threadIdx.x;
  if (tid >= nks * 8 * 64) return;
  const int l = tid & 63;
  const int c = (tid >> 6) & 7;
  const int kk = tid >> 9;
  union { ushort u[8]; uint4 v; } o;
  #pragma unroll
  for (int j = 0; j < 8; ++j) {
    const int k = kk * 32 + ((l >> 4) * 8) + j;
    const float f = (k < Korig) ? W[k * HID + c * 16 + (l & 15)] : 0.0f;
    o.u[j] = f2bf(f);
  }
  reinterpret_cast<uint4*>(out)[tid] = o.v;
}

// 64 edges/block, 4 waves. bf16 MFMA 2-layer edge MLP + f32 atomic scatter.
__global__ __launch_bounds__(256, 2)
void edge_kernel(const ushort* __restrict__ hb, const float* __restrict__ pos,
                 const int* __restrict__ edge_index, const int* __restrict__ edge_type,
                 const float* __restrict__ emb,
                 const ushort* __restrict__ w1p, const float* __restrict__ mb1,
                 const ushort* __restrict__ w2p, const float* __restrict__ mb2,
                 float* __restrict__ sums)
{
  __shared__ ushort sA[TILE_E * KP];    // 57.3 KB, XOR-swizzled rows (stride 896B)
  __shared__ ushort sX[TILE_E * HID];   // 16 KB, XOR-swizzled rows (stride 256B)
  __shared__ int   sSrc[TILE_E];
  __shared__ int   sDst[TILE_E];
  __shared__ int   sEt[TILE_E];
  __shared__ float sDistF[TILE_E];

  const int t  = threadIdx.x;
  const int e0 = blockIdx.x * TILE_E;

  if (t < TILE_E) {
    const int e = e0 + t;
    const int s = edge_index[e];
    const int d = edge_index[NE + e];
    sSrc[t] = s; sDst[t] = d; sEt[t] = edge_type[e];
    const float dx = pos[3*s]   - pos[3*d];
    const float dy = pos[3*s+1] - pos[3*d+1];
    const float dz = pos[3*s+2] - pos[3*d+2];
    sDistF[t] = sqrtf(dx*dx + dy*dy + dz*dz);
  }
  __syncthreads();

  // ---- build A tile: [h_src | h_dst | emb | rbf | dist | pad] in bf16 ----
  char* const sAb = reinterpret_cast<char*>(sA);
  for (int q = t; q < TILE_E * 16; q += 256) {      // 4 iters; 16B chunks
    const int e = q >> 4, c8 = q & 15;
    char* const rowb = sAb + e * (KP * 2);
    const int sm = (e & 7) << 4;
    // h[src]
    uint4 v = *reinterpret_cast<const uint4*>(hb + (long)sSrc[e] * HID + c8 * 8);
    *reinterpret_cast<uint4*>(rowb + ((c8 * 16) ^ sm)) = v;
    // h[dst]
    v = *reinterpret_cast<const uint4*>(hb + (long)sDst[e] * HID + c8 * 8);
    *reinterpret_cast<uint4*>(rowb + ((256 + c8 * 16) ^ sm)) = v;
    // emb[edge_type] (f32 -> bf16 inline; only 2 rows, L1-hot)
    const float4 f0 = *reinterpret_cast<const float4*>(emb + sEt[e] * HID + c8 * 8);
    const float4 f1 = *reinterpret_cast<const float4*>(emb + sEt[e] * HID + c8 * 8 + 4);
    union { ushort u[8]; uint4 w; } o;
    o.u[0]=f2bf(f0.x); o.u[1]=f2bf(f0.y); o.u[2]=f2bf(f0.z); o.u[3]=f2bf(f0.w);
    o.u[4]=f2bf(f1.x); o.u[5]=f2bf(f1.y); o.u[6]=f2bf(f1.z); o.u[7]=f2bf(f1.w);
    *reinterpret_cast<uint4*>(rowb + ((512 + c8 * 16) ^ sm)) = o.w;
  }
  {  // rbf: 64 rows x 32, one 16B chunk per thread
    const int e = t >> 2, r0 = (t & 3) * 8;
    const float step  = 6.0f / 31.0f;
    const float gamma = 1.0f / (step * step);
    const float dist = sDistF[e];
    union { ushort u[8]; uint4 w; } o;
    #pragma unroll
    for (int j = 0; j < 8; ++j) {
      const float dd = dist - step * (float)(r0 + j);
      o.u[j] = f2bf(__expf(-gamma * dd * dd));
    }
    char* const rowb = sAb + e * (KP * 2);
    const int sm = (e & 7) << 4;
    *reinterpret_cast<uint4*>(rowb + ((768 + (t & 3) * 16) ^ sm)) = o.w;
  }
  if (t < TILE_E) {  // dist (col 416) + zero pad to 448
    union { ushort u[8]; uint4 w; } z;
    #pragma unroll
    for (int j = 0; j < 8; ++j) z.u[j] = 0;
    char* const rowb = sAb + t * (KP * 2);
    const int sm = (t & 7) << 4;
    z.u[0] = f2bf(sDistF[t]);
    *reinterpret_cast<uint4*>(rowb + (832 ^ sm)) = z.w;
    z.u[0] = 0;
    *reinterpret_cast<uint4*>(rowb + (848 ^ sm)) = z.w;
    *reinterpret_cast<uint4*>(rowb + (864 ^ sm)) = z.w;
    *reinterpret_cast<uint4*>(rowb + (880 ^ sm)) = z.w;
  }
  __syncthreads();

  // ---- wave tiling: wave w owns 2 row-tiles x 4 col-tiles of the 64x128 output ----
  const int lane = t & 63;
  const int w    = t >> 6;
  const int rt0  = (w & 1) * 2;        // row-tile base (16-edge tiles)
  const int ct0  = (w >> 1) * 4;       // col-tile base (16-col tiles)
  const int lrow = lane & 15;
  const int lk16 = (lane >> 4) * 16;   // byte offset of k-group within a 64B k-step

  const int rowA0 = rt0 * 16 + lrow;
  const int rowA1 = rowA0 + 16;
  const int smA0 = (rowA0 & 7) << 4;
  const int smA1 = (rowA1 & 7) << 4;

  // ---- GEMM1: [64 x 448] @ [448 x 128] ----
  floatx4 acc[2][4] = {};
  {
    const ushort* const bbase = w1p + ((size_t)ct0 * 64 + lane) * 8;
    #pragma unroll 2
    for (int kk = 0; kk < NKS1; ++kk) {
      short8 bfr[4];
      #pragma unroll
      for (int j = 0; j < 4; ++j)
        bfr[j] = *reinterpret_cast<const short8*>(bbase + kk * 4096 + j * 512);
      short8 afr[2];
      afr[0] = *reinterpret_cast<const short8*>(sAb + rowA0 * (KP*2) + ((kk*64 + lk16) ^ smA0));
      afr[1] = *reinterpret_cast<const short8*>(sAb + rowA1 * (KP*2) + ((kk*64 + lk16) ^ smA1));
      #pragma unroll
      for (int i = 0; i < 2; ++i)
        #pragma unroll
        for (int j = 0; j < 4; ++j)
          acc[i][j] = __builtin_amdgcn_mfma_f32_16x16x32_bf16(afr[i], bfr[j], acc[i][j], 0, 0, 0);
    }
  }

  // epilogue 1: bias + silu -> sX (bf16, swizzled)
  char* const sXb = reinterpret_cast<char*>(sX);
  {
    float b1v[4];
    #pragma unroll
    for (int j = 0; j < 4; ++j) b1v[j] = mb1[(ct0 + j) * 16 + lrow];
    #pragma unroll
    for (int i = 0; i < 2; ++i) {
      #pragma unroll
      for (int r = 0; r < 4; ++r) {
        const int row = (rt0 + i) * 16 + (lane >> 4) * 4 + r;
        const int sm = (row & 7) << 4;
        #pragma unroll
        for (int j = 0; j < 4; ++j) {
          const ushort bv = f2bf(silu_f(acc[i][j][r] + b1v[j]));
          const int col = (ct0 + j) * 16 + lrow;
          *reinterpret_cast<ushort*>(sXb + row * 256 + ((col * 2) ^ sm)) = bv;
        }
      }
    }
  }
  __syncthreads();

  // ---- GEMM2: [64 x 128] @ [128 x 128] ----
  floatx4 acc2[2][4] = {};
  {
    const ushort* const bbase = w2p + ((size_t)ct0 * 64 + lane) * 8;
    #pragma unroll
    for (int kk = 0; kk < NKS2; ++kk) {
      short8 bfr[4];
      #pragma unroll
      for (int j = 0; j < 4; ++j)
        bfr[j] = *reinterpret_cast<const short8*>(bbase + kk * 4096 + j * 512);
      short8 afr[2];
      afr[0] = *reinterpret_cast<const short8*>(sXb + rowA0 * 256 + ((kk*64 + lk16) ^ smA0));
      afr[1] = *reinterpret_cast<const short8*>(sXb + rowA1 * 256 + ((kk*64 + lk16) ^ smA1));
      #pragma unroll
      for (int i = 0; i < 2; ++i)
        #pragma unroll
        for (int j = 0; j < 4; ++j)
          acc2[i][j] = __builtin_amdgcn_mfma_f32_16x16x32_bf16(afr[i], bfr[j], acc2[i][j], 0, 0, 0);
    }
  }

  // epilogue 2: bias + silu + atomic scatter into sums[dst]
  {
    float b2v[4];
    #pragma unroll
    for (int j = 0; j < 4; ++j) b2v[j] = mb2[(ct0 + j) * 16 + lrow];
    #pragma unroll
    for (int i = 0; i < 2; ++i) {
      #pragma unroll
      for (int r = 0; r < 4; ++r) {
        const int row = (rt0 + i) * 16 + (lane >> 4) * 4 + r;
        const long dbase = (long)sDst[row] * HID;
        #pragma unroll
        for (int j = 0; j < 4; ++j) {
          const float v = silu_f(acc2[i][j][r] + b2v[j]);
          atomicAdd(&sums[dbase + (ct0 + j) * 16 + lrow], v);
        }
      }
    }
  }
}

// 64 nodes per block: node MLP + residual + LayerNorm + ligand mask. (unchanged)
__global__ __launch_bounds__(256, 1)
void node_kernel(const float* __restrict__ h,
                 const float* __restrict__ sums, const float* __restrict__ counts,
                 const int* __restrict__ node_type,
                 const float* __restrict__ uw1, const float* __restrict__ ub1,
                 const float* __restrict__ uw2, const float* __restrict__ ub2,
                 const float* __restrict__ ln_g, const float* __restrict__ ln_b,
                 float* __restrict__ out)
{
  __shared__ float sIn[TILE_N * 256];
  __shared__ float sU[TILE_N * HID];
  __shared__ float sMu[TILE_N];
  __shared__ float sRs[TILE_N];

  const int t  = threadIdx.x;
  const int n0 = blockIdx.x * TILE_N;

  for (int idx = t; idx < TILE_N*HID; idx += 256) {
    const int n = idx >> 7, c = idx & (HID-1);
    const int node = n0 + n;
    float hv = 0.f, av = 0.f;
    if (node < NN) {
      hv = h[(long)node*HID + c];
      av = sums[(long)node*HID + c] / fmaxf(counts[node], 1.0f);
    }
    sIn[n*256 + c]       = hv;
    sIn[n*256 + HID + c] = av;
  }
  __syncthreads();

  const int tx = t & 31;
  const int ty = t >> 5;

  const float* wp = uw1 + tx*4;
  float4 acc[8];
  #pragma unroll
  for (int i = 0; i < 8; ++i) acc[i] = make_float4(0.f,0.f,0.f,0.f);
  for (int k = 0; k < 2*HID; ++k) {
    const float4 w = *reinterpret_cast<const float4*>(wp + (long)k*HID);
    #pragma unroll
    for (int i = 0; i < 8; ++i) {
      const float a = sIn[(ty*8+i)*256 + k];
      acc[i].x = fmaf(a, w.x, acc[i].x);
      acc[i].y = fmaf(a, w.y, acc[i].y);
      acc[i].z = fmaf(a, w.z, acc[i].z);
      acc[i].w = fmaf(a, w.w, acc[i].w);
    }
  }
  const float4 b1 = *reinterpret_cast<const float4*>(ub1 + tx*4);
  #pragma unroll
  for (int i = 0; i < 8; ++i) {
    const int e = ty*8 + i;
    float4 v = acc[i];
    v.x = silu_f(v.x + b1.x); v.y = silu_f(v.y + b1.y);
    v.z = silu_f(v.z + b1.z); v.w = silu_f(v.w + b1.w);
    *reinterpret_cast<float4*>(&sU[e*HID + tx*4]) = v;
  }
  __syncthreads();

  const float* wp2 = uw2 + tx*4;
  float4 acc2[8];
  #pragma unroll
  for (int i = 0; i < 8; ++i) acc2[i] = make_float4(0.f,0.f,0.f,0.f);
  for (int k = 0; k < HID; ++k) {
    const float4 w = *reinterpret_cast<const float4*>(wp2 + (long)k*HID);
    #pragma unroll
    for (int i = 0; i < 8; ++i) {
      const float a = sU[(ty*8+i)*HID + k];
      acc2[i].x = fmaf(a, w.x, acc2[i].x);
      acc2[i].y = fmaf(a, w.y, acc2[i].y);
      acc2[i].z = fmaf(a, w.z, acc2[i].z);
      acc2[i].w = fmaf(a, w.w, acc2[i].w);
    }
  }
  __syncthreads();

  const float4 b2 = *reinterpret_cast<const float4*>(ub2 + tx*4);
  #pragma unroll
  for (int i = 0; i < 8; ++i) {
    const int e = ty*8 + i;
    float4 v = acc2[i];
    v.x = sIn[e*256 + tx*4+0] + v.x + b2.x;
    v.y = sIn[e*256 + tx*4+1] + v.y + b2.y;
    v.z = sIn[e*256 + tx*4+2] + v.z + b2.z;
    v.w = sIn[e*256 + tx*4+3] + v.w + b2.w;
    *reinterpret_cast<float4*>(&sU[e*HID + tx*4]) = v;
  }
  __syncthreads();

  {
    const int n = t >> 2, q = t & 3;
    float sm = 0.f, sq = 0.f;
    #pragma unroll 8
    for (int i = 0; i < 32; ++i) {
      const float v = sU[n*HID + q*32 + i];
      sm += v; sq += v*v;
    }
    sm += __shfl_xor(sm, 1); sq += __shfl_xor(sq, 1);
    sm += __shfl_xor(sm, 2); sq += __shfl_xor(sq, 2);
    const float mu  = sm * (1.0f/HID);
    float var = sq * (1.0f/HID) - mu*mu;
    var = fmaxf(var, 0.0f);
    if (q == 0) { sMu[n] = mu; sRs[n] = rsqrtf(var + 1e-5f); }
  }
  __syncthreads();

  for (int idx = t; idx < TILE_N*HID; idx += 256) {
    const int n = idx >> 7, c = idx & (HID-1);
    const int node = n0 + n;
    if (node >= NN) continue;
    const float xv = sU[n*HID + c];
    const float normed = (xv - sMu[n]) * sRs[n] * ln_g[c] + ln_b[c];
    const float hv = sIn[n*256 + c];
    out[(long)node*HID + c] = (node_type[node] == 0) ? normed : hv;
  }
}

extern "C" void kernel_launch(void* const* d_in, const int* in_sizes, int n_in,
                              void* d_out, int out_size, void* d_ws, size_t ws_size,
                              hipStream_t stream)
{
  const float* h    = (const float*)d_in[0];
  const float* pos  = (const float*)d_in[1];
  const int*   eidx = (const int*)  d_in[2];
  const int*   etyp = (const int*)  d_in[3];
  const int*   ntyp = (const int*)  d_in[4];
  const float* emb  = (const float*)d_in[5];
  const float* mw1  = (const float*)d_in[6];
  const float* mb1  = (const float*)d_in[7];
  const float* mw2  = (const float*)d_in[8];
  const float* mb2  = (const float*)d_in[9];
  const float* uw1  = (const float*)d_in[10];
  const float* ub1  = (const float*)d_in[11];
  const float* uw2  = (const float*)d_in[12];
  const float* ub2  = (const float*)d_in[13];
  const float* lng  = (const float*)d_in[14];
  const float* lnb  = (const float*)d_in[15];

  // workspace layout
  float*  sums   = (float*)d_ws;                    // 25.6 MB
  float*  counts = sums + (long)NN*HID;             // 200 KB
  ushort* hb     = (ushort*)(counts + NN);          // 12.8 MB
  ushort* w1p    = hb + (long)NN*HID;               // 14*8*64*8 = 57344 elems
  ushort* w2p    = w1p + NKS1*8*64*8;               // 4*8*64*8 = 16384 elems

  zero_kernel<<<2048, 256, 0, stream>>>(sums, NN*HID + NN);
  convert_h_kernel<<<(NN*HID/8 + 255)/256, 256, 0, stream>>>(h, hb);
  pack_w_kernel<<<(NKS1*8*64 + 255)/256, 256, 0, stream>>>(mw1, w1p, DIN, NKS1);
  pack_w_kernel<<<(NKS2*8*64 + 255)/256, 256, 0, stream>>>(mw2, w2p, HID, NKS2);
  counts_kernel<<<(NE + 255)/256, 256, 0, stream>>>(eidx, counts);
  edge_kernel<<<NE/TILE_E, 256, 0, stream>>>(hb, pos, eidx, etyp, emb,
                                             w1p, mb1, w2p, mb2, sums);
  node_kernel<<<(NN + TILE_N - 1)/TILE_N, 256, 0, stream>>>(h, sums, counts, ntyp,
                                                            uw1, ub1, uw2, ub2,
                                                            lng, lnb, (float*)d_out);
}

// Round 5
// 628.065 us; speedup vs baseline: 5.1179x; 1.0899x over previous
//
#include <hip/hip_runtime.h>
#include <hip/hip_bf16.h>
#include <math.h>

#define NN   50000
#define NE   800000
#define HID  128
#define NRBF 32

typedef __attribute__((ext_vector_type(8))) short short8;   // 8 bf16
typedef __attribute__((ext_vector_type(4))) float floatx4;  // MFMA acc

constexpr int TILE_N = 64;

__device__ __forceinline__ float silu_f(float x) {
  return x / (1.0f + __expf(-x));
}
__device__ __forceinline__ ushort f2bf(float f) {
  __hip_bfloat16 b = __float2bfloat16(f);
  return *reinterpret_cast<ushort*>(&b);
}
__device__ __forceinline__ float bf2f(ushort u) {
  union { uint u32; float f; } c; c.u32 = ((uint)u) << 16; return c.f;
}

__global__ void counts_kernel(const int* __restrict__ edge_index, float* __restrict__ counts) {
  const int e = blockIdx.x * blockDim.x + threadIdx.x;
  if (e < NE) atomicAdd(&counts[edge_index[NE + e]], 1.0f);
}

// embp[2][128] = emb @ mw1[256:384] + mb1   (f32, bias folded)
__global__ void embp_kernel(const float* __restrict__ emb, const float* __restrict__ mw1,
                            const float* __restrict__ mb1, float* __restrict__ embp) {
  const int t = threadIdx.x;
  const int row = t >> 7, col = t & 127;
  float s = mb1[col];
  for (int k = 0; k < HID; ++k)
    s = fmaf(emb[row * HID + k], mw1[(256 + k) * HID + col], s);
  embp[row * HID + col] = s;
}

// Pack W [Korig x 128] f32 into bf16 MFMA B-fragment order:
// out[((kk*8 + c)*64 + lane)*8 + j] = W[kk*32 + (lane>>4)*8 + j][c*16 + (lane&15)]
__global__ void pack_w_kernel(const float* __restrict__ W, ushort* __restrict__ out,
                              int Korig, int nks) {
  const int tid = blockIdx.x * blockDim.x + threadIdx.x;
  if (tid >= nks * 8 * 64) return;
  const int l = tid & 63;
  const int c = (tid >> 6) & 7;
  const int kk = tid >> 9;
  union { ushort u[8]; uint4 v; } o;
  #pragma unroll
  for (int j = 0; j < 8; ++j) {
    const int k = kk * 32 + ((l >> 4) * 8) + j;
    const float f = (k < Korig) ? W[k * HID + c * 16 + (l & 15)] : 0.0f;
    o.u[j] = f2bf(f);
  }
  reinterpret_cast<uint4*>(out)[tid] = o.v;
}

// hs_proj = h @ mw1[0:128], hd_proj = h @ mw1[128:256]  (bf16 out)
__global__ __launch_bounds__(256, 3)
void proj_kernel(const float* __restrict__ h,
                 const ushort* __restrict__ wap, const ushort* __restrict__ wbp,
                 ushort* __restrict__ hs_proj, ushort* __restrict__ hd_proj)
{
  __shared__ __align__(16) ushort sH[64 * HID];   // 16 KB, swizzled
  char* const sHb = reinterpret_cast<char*>(sH);
  const int t  = threadIdx.x;
  const int n0 = blockIdx.x * 64;

  {  // build A tile (f32 -> bf16)
    const int e = t >> 2, c0 = (t & 3) * 32;
    const int node = n0 + e;
    const int sm = (e & 7) << 4;
    #pragma unroll
    for (int m = 0; m < 4; ++m) {
      const int c = c0 + m * 8;
      float4 f0 = make_float4(0,0,0,0), f1 = f0;
      if (node < NN) {
        f0 = *reinterpret_cast<const float4*>(h + (long)node * HID + c);
        f1 = *reinterpret_cast<const float4*>(h + (long)node * HID + c + 4);
      }
      union { ushort u[8]; uint4 v; } o;
      o.u[0]=f2bf(f0.x); o.u[1]=f2bf(f0.y); o.u[2]=f2bf(f0.z); o.u[3]=f2bf(f0.w);
      o.u[4]=f2bf(f1.x); o.u[5]=f2bf(f1.y); o.u[6]=f2bf(f1.z); o.u[7]=f2bf(f1.w);
      *reinterpret_cast<uint4*>(sHb + ((e * 256 + c * 2) ^ sm)) = o.v;
    }
  }
  __syncthreads();

  const int lane = t & 63;
  const int w    = t >> 6;
  const int rt0  = (w & 1) * 2;
  const int ct0  = (w >> 1) * 4;
  const int lrow = lane & 15;
  const int lk16 = (lane >> 4) * 16;
  const int rowA0 = rt0 * 16 + lrow, rowA1 = rowA0 + 16;
  const int smA0 = (rowA0 & 7) << 4, smA1 = (rowA1 & 7) << 4;

  floatx4 accA[2][4] = {}, accB[2][4] = {};
  const ushort* const baseA = wap + ((size_t)ct0 * 64 + lane) * 8;
  const ushort* const baseB = wbp + ((size_t)ct0 * 64 + lane) * 8;
  #pragma unroll
  for (int kk = 0; kk < 4; ++kk) {
    short8 afr[2];
    afr[0] = *reinterpret_cast<const short8*>(sHb + rowA0 * 256 + ((kk*64 + lk16) ^ smA0));
    afr[1] = *reinterpret_cast<const short8*>(sHb + rowA1 * 256 + ((kk*64 + lk16) ^ smA1));
    #pragma unroll
    for (int j = 0; j < 4; ++j) {
      const short8 bA = *reinterpret_cast<const short8*>(baseA + kk * 4096 + j * 512);
      const short8 bB = *reinterpret_cast<const short8*>(baseB + kk * 4096 + j * 512);
      #pragma unroll
      for (int i = 0; i < 2; ++i) {
        accA[i][j] = __builtin_amdgcn_mfma_f32_16x16x32_bf16(afr[i], bA, accA[i][j], 0, 0, 0);
        accB[i][j] = __builtin_amdgcn_mfma_f32_16x16x32_bf16(afr[i], bB, accB[i][j], 0, 0, 0);
      }
    }
  }
  #pragma unroll
  for (int i = 0; i < 2; ++i)
    #pragma unroll
    for (int r = 0; r < 4; ++r) {
      const int row = (rt0 + i) * 16 + (lane >> 4) * 4 + r;
      const int node = n0 + row;
      if (node < NN) {
        #pragma unroll
        for (int j = 0; j < 4; ++j) {
          const int col = (ct0 + j) * 16 + lrow;
          hs_proj[(long)node * HID + col] = f2bf(accA[i][j][r]);
          hd_proj[(long)node * HID + col] = f2bf(accB[i][j][r]);
        }
      }
    }
}

// 64 edges/block: pre-sum gather + K=32 rbf MFMA + silu + K=128 GEMM2 + f32 atomic scatter
__global__ __launch_bounds__(256, 3)
void edge_kernel(const ushort* __restrict__ hs_proj, const ushort* __restrict__ hd_proj,
                 const float* __restrict__ pos,
                 const int* __restrict__ edge_index, const int* __restrict__ edge_type,
                 const float* __restrict__ embp, const float* __restrict__ w416,
                 const ushort* __restrict__ w1dp, const ushort* __restrict__ w2p,
                 const float* __restrict__ mb2,
                 float* sums)
{
  __shared__ __align__(16) uint4  sRbf[64 * 4];      // 4 KB
  __shared__ __align__(16) float  sPre[64 * HID];    // 32 KB, swizzled
  __shared__ __align__(16) ushort sX[64 * HID];      // 16 KB, swizzled
  __shared__ int   sSrc[64], sDst[64], sEt[64];
  __shared__ float sDist[64];
  char* const sPreB = reinterpret_cast<char*>(sPre);
  char* const sXb   = reinterpret_cast<char*>(sX);

  const int t  = threadIdx.x;
  const int e0 = blockIdx.x * 64;

  if (t < 64) {
    const int e = e0 + t;
    const int s = edge_index[e];
    const int d = edge_index[NE + e];
    sSrc[t] = s; sDst[t] = d; sEt[t] = edge_type[e];
    const float dx = pos[3*s]   - pos[3*d];
    const float dy = pos[3*s+1] - pos[3*d+1];
    const float dz = pos[3*s+2] - pos[3*d+2];
    sDist[t] = sqrtf(dx*dx + dy*dy + dz*dz);
  }
  __syncthreads();

  {  // pre-sum + rbf build
    const int e = t >> 2, q = t & 3;
    const int c0 = q * 32;
    const int src = sSrc[e], et = sEt[e];
    const float dist = sDist[e];
    const ushort* const hsr = hs_proj + (long)src * HID;
    const ushort* const hdr = hd_proj + (long)sDst[e] * HID;
    const float*  const ep  = embp + et * HID;
    const int sm = (e & 7) << 4;
    #pragma unroll
    for (int m = 0; m < 4; ++m) {
      const int c = c0 + m * 8;
      const uint4 a = *reinterpret_cast<const uint4*>(hsr + c);
      const uint4 b = *reinterpret_cast<const uint4*>(hdr + c);
      const float4 ef0 = *reinterpret_cast<const float4*>(ep + c);
      const float4 ef1 = *reinterpret_cast<const float4*>(ep + c + 4);
      const float4 w0  = *reinterpret_cast<const float4*>(w416 + c);
      const float4 w1  = *reinterpret_cast<const float4*>(w416 + c + 4);
      const ushort* au = reinterpret_cast<const ushort*>(&a);
      const ushort* bu = reinterpret_cast<const ushort*>(&b);
      float4 o0, o1;
      o0.x = bf2f(au[0]) + bf2f(bu[0]) + ef0.x + dist * w0.x;
      o0.y = bf2f(au[1]) + bf2f(bu[1]) + ef0.y + dist * w0.y;
      o0.z = bf2f(au[2]) + bf2f(bu[2]) + ef0.z + dist * w0.z;
      o0.w = bf2f(au[3]) + bf2f(bu[3]) + ef0.w + dist * w0.w;
      o1.x = bf2f(au[4]) + bf2f(bu[4]) + ef1.x + dist * w1.x;
      o1.y = bf2f(au[5]) + bf2f(bu[5]) + ef1.y + dist * w1.y;
      o1.z = bf2f(au[6]) + bf2f(bu[6]) + ef1.z + dist * w1.z;
      o1.w = bf2f(au[7]) + bf2f(bu[7]) + ef1.w + dist * w1.w;
      const int byte0 = e * 512 + c * 4;
      *reinterpret_cast<float4*>(sPreB + (byte0 ^ sm))        = o0;
      *reinterpret_cast<float4*>(sPreB + ((byte0 + 16) ^ sm)) = o1;
    }
    // rbf [64][32] bf16, frag-chunked [row][kg] with kg ^ (row&3)
    const float step  = 6.0f / 31.0f;
    const float gamma = 1.0f / (step * step);
    const int r0 = q * 8;
    union { ushort u[8]; uint4 v; } o;
    #pragma unroll
    for (int j = 0; j < 8; ++j) {
      const float dd = dist - step * (float)(r0 + j);
      o.u[j] = f2bf(__expf(-gamma * dd * dd));
    }
    sRbf[e * 4 + (q ^ (e & 3))] = o.v;
  }
  __syncthreads();

  const int lane = t & 63;
  const int w    = t >> 6;
  const int rt0  = (w & 1) * 2;
  const int ct0  = (w >> 1) * 4;
  const int lrow = lane & 15;
  const int lk16 = (lane >> 4) * 16;
  const int rowA0 = rt0 * 16 + lrow, rowA1 = rowA0 + 16;

  // ---- layer 1: acc = pre (C-layout reads) + rbf @ W1d (one k-step) ----
  floatx4 acc[2][4];
  #pragma unroll
  for (int i = 0; i < 2; ++i)
    #pragma unroll
    for (int r = 0; r < 4; ++r) {
      const int row = (rt0 + i) * 16 + (lane >> 4) * 4 + r;
      const int sm = (row & 7) << 4;
      #pragma unroll
      for (int j = 0; j < 4; ++j) {
        const int col = (ct0 + j) * 16 + lrow;
        acc[i][j][r] = *reinterpret_cast<const float*>(sPreB + ((row * 512 + col * 4) ^ sm));
      }
    }
  {
    short8 a0 = *reinterpret_cast<const short8*>(&sRbf[rowA0 * 4 + ((lane >> 4) ^ (rowA0 & 3))]);
    short8 a1 = *reinterpret_cast<const short8*>(&sRbf[rowA1 * 4 + ((lane >> 4) ^ (rowA1 & 3))]);
    #pragma unroll
    for (int j = 0; j < 4; ++j) {
      const short8 b = *reinterpret_cast<const short8*>(w1dp + ((size_t)(ct0 + j) * 64 + lane) * 8);
      acc[0][j] = __builtin_amdgcn_mfma_f32_16x16x32_bf16(a0, b, acc[0][j], 0, 0, 0);
      acc[1][j] = __builtin_amdgcn_mfma_f32_16x16x32_bf16(a1, b, acc[1][j], 0, 0, 0);
    }
  }
  // silu -> sX (bf16, swizzled). mb1 already folded into embp.
  #pragma unroll
  for (int i = 0; i < 2; ++i)
    #pragma unroll
    for (int r = 0; r < 4; ++r) {
      const int row = (rt0 + i) * 16 + (lane >> 4) * 4 + r;
      const int sm = (row & 7) << 4;
      #pragma unroll
      for (int j = 0; j < 4; ++j) {
        const int col = (ct0 + j) * 16 + lrow;
        *reinterpret_cast<ushort*>(sXb + row * 256 + ((col * 2) ^ sm)) = f2bf(silu_f(acc[i][j][r]));
      }
    }
  __syncthreads();

  // ---- layer 2: [64 x 128] @ [128 x 128] ----
  floatx4 acc2[2][4] = {};
  {
    const int smA0 = (rowA0 & 7) << 4, smA1 = (rowA1 & 7) << 4;
    const ushort* const bbase = w2p + ((size_t)ct0 * 64 + lane) * 8;
    #pragma unroll 2
    for (int kk = 0; kk < 4; ++kk) {
      short8 bfr[4];
      #pragma unroll
      for (int j = 0; j < 4; ++j)
        bfr[j] = *reinterpret_cast<const short8*>(bbase + kk * 4096 + j * 512);
      short8 afr[2];
      afr[0] = *reinterpret_cast<const short8*>(sXb + rowA0 * 256 + ((kk*64 + lk16) ^ smA0));
      afr[1] = *reinterpret_cast<const short8*>(sXb + rowA1 * 256 + ((kk*64 + lk16) ^ smA1));
      #pragma unroll
      for (int i = 0; i < 2; ++i)
        #pragma unroll
        for (int j = 0; j < 4; ++j)
          acc2[i][j] = __builtin_amdgcn_mfma_f32_16x16x32_bf16(afr[i], bfr[j], acc2[i][j], 0, 0, 0);
    }
  }

  // epilogue: bias + silu + f32 atomic scatter
  {
    float b2v[4];
    #pragma unroll
    for (int j = 0; j < 4; ++j) b2v[j] = mb2[(ct0 + j) * 16 + lrow];
    #pragma unroll
    for (int i = 0; i < 2; ++i)
      #pragma unroll
      for (int r = 0; r < 4; ++r) {
        const int row = (rt0 + i) * 16 + (lane >> 4) * 4 + r;
        const long dbase = (long)sDst[row] * HID;
        #pragma unroll
        for (int j = 0; j < 4; ++j) {
          const float v = silu_f(acc2[i][j][r] + b2v[j]);
          atomicAdd(&sums[dbase + (ct0 + j) * 16 + lrow], v);
        }
      }
  }
}

// R1-proven f32 VALU node kernel: node MLP + residual + LayerNorm + ligand mask.
// NOTE: sums aliases out (d_out) — no __restrict__ on either. Each block reads
// sums only for its own 64 nodes before writing out for those same nodes.
__global__ __launch_bounds__(256, 1)
void node_kernel(const float* __restrict__ h,
                 const float* sums, const float* __restrict__ counts,
                 const int* __restrict__ node_type,
                 const float* __restrict__ uw1, const float* __restrict__ ub1,
                 const float* __restrict__ uw2, const float* __restrict__ ub2,
                 const float* __restrict__ ln_g, const float* __restrict__ ln_b,
                 float* out)
{
  __shared__ float sIn[TILE_N * 256];   // 64 KB: [h, agg]
  __shared__ float sU[TILE_N * HID];    // 32 KB
  __shared__ float sMu[TILE_N];
  __shared__ float sRs[TILE_N];

  const int t  = threadIdx.x;
  const int n0 = blockIdx.x * TILE_N;

  for (int idx = t; idx < TILE_N*HID; idx += 256) {
    const int n = idx >> 7, c = idx & (HID-1);
    const int node = n0 + n;
    float hv = 0.f, av = 0.f;
    if (node < NN) {
      hv = h[(long)node*HID + c];
      av = sums[(long)node*HID + c] / fmaxf(counts[node], 1.0f);
    }
    sIn[n*256 + c]       = hv;
    sIn[n*256 + HID + c] = av;
  }
  __syncthreads();

  const int tx = t & 31;
  const int ty = t >> 5;

  const float* wp = uw1 + tx*4;
  float4 acc[8];
  #pragma unroll
  for (int i = 0; i < 8; ++i) acc[i] = make_float4(0.f,0.f,0.f,0.f);
  for (int k = 0; k < 2*HID; ++k) {
    const float4 w = *reinterpret_cast<const float4*>(wp + (long)k*HID);
    #pragma unroll
    for (int i = 0; i < 8; ++i) {
      const float a = sIn[(ty*8+i)*256 + k];
      acc[i].x = fmaf(a, w.x, acc[i].x);
      acc[i].y = fmaf(a, w.y, acc[i].y);
      acc[i].z = fmaf(a, w.z, acc[i].z);
      acc[i].w = fmaf(a, w.w, acc[i].w);
    }
  }
  const float4 b1 = *reinterpret_cast<const float4*>(ub1 + tx*4);
  #pragma unroll
  for (int i = 0; i < 8; ++i) {
    const int e = ty*8 + i;
    float4 v = acc[i];
    v.x = silu_f(v.x + b1.x); v.y = silu_f(v.y + b1.y);
    v.z = silu_f(v.z + b1.z); v.w = silu_f(v.w + b1.w);
    *reinterpret_cast<float4*>(&sU[e*HID + tx*4]) = v;
  }
  __syncthreads();

  const float* wp2 = uw2 + tx*4;
  float4 acc2[8];
  #pragma unroll
  for (int i = 0; i < 8; ++i) acc2[i] = make_float4(0.f,0.f,0.f,0.f);
  for (int k = 0; k < HID; ++k) {
    const float4 w = *reinterpret_cast<const float4*>(wp2 + (long)k*HID);
    #pragma unroll
    for (int i = 0; i < 8; ++i) {
      const float a = sU[(ty*8+i)*HID + k];
      acc2[i].x = fmaf(a, w.x, acc2[i].x);
      acc2[i].y = fmaf(a, w.y, acc2[i].y);
      acc2[i].z = fmaf(a, w.z, acc2[i].z);
      acc2[i].w = fmaf(a, w.w, acc2[i].w);
    }
  }
  __syncthreads();

  const float4 b2 = *reinterpret_cast<const float4*>(ub2 + tx*4);
  #pragma unroll
  for (int i = 0; i < 8; ++i) {
    const int e = ty*8 + i;
    float4 v = acc2[i];
    v.x = sIn[e*256 + tx*4+0] + v.x + b2.x;
    v.y = sIn[e*256 + tx*4+1] + v.y + b2.y;
    v.z = sIn[e*256 + tx*4+2] + v.z + b2.z;
    v.w = sIn[e*256 + tx*4+3] + v.w + b2.w;
    *reinterpret_cast<float4*>(&sU[e*HID + tx*4]) = v;
  }
  __syncthreads();

  {
    const int n = t >> 2, q = t & 3;
    float sm = 0.f, sq = 0.f;
    #pragma unroll 8
    for (int i = 0; i < 32; ++i) {
      const float v = sU[n*HID + q*32 + i];
      sm += v; sq += v*v;
    }
    sm += __shfl_xor(sm, 1); sq += __shfl_xor(sq, 1);
    sm += __shfl_xor(sm, 2); sq += __shfl_xor(sq, 2);
    const float mu  = sm * (1.0f/HID);
    float var = sq * (1.0f/HID) - mu*mu;
    var = fmaxf(var, 0.0f);
    if (q == 0) { sMu[n] = mu; sRs[n] = rsqrtf(var + 1e-5f); }
  }
  __syncthreads();

  for (int idx = t; idx < TILE_N*HID; idx += 256) {
    const int n = idx >> 7, c = idx & (HID-1);
    const int node = n0 + n;
    if (node >= NN) continue;
    const float xv = sU[n*HID + c];
    const float normed = (xv - sMu[n]) * sRs[n] * ln_g[c] + ln_b[c];
    const float hv = sIn[n*256 + c];
    out[(long)node*HID + c] = (node_type[node] == 0) ? normed : hv;
  }
}

extern "C" void kernel_launch(void* const* d_in, const int* in_sizes, int n_in,
                              void* d_out, int out_size, void* d_ws, size_t ws_size,
                              hipStream_t stream)
{
  const float* h    = (const float*)d_in[0];
  const float* pos  = (const float*)d_in[1];
  const int*   eidx = (const int*)  d_in[2];
  const int*   etyp = (const int*)  d_in[3];
  const int*   ntyp = (const int*)  d_in[4];
  const float* emb  = (const float*)d_in[5];
  const float* mw1  = (const float*)d_in[6];
  const float* mb1  = (const float*)d_in[7];
  const float* mw2  = (const float*)d_in[8];
  const float* mb2  = (const float*)d_in[9];
  const float* uw1  = (const float*)d_in[10];
  const float* ub1  = (const float*)d_in[11];
  const float* uw2  = (const float*)d_in[12];
  const float* ub2  = (const float*)d_in[13];
  const float* lng  = (const float*)d_in[14];
  const float* lnb  = (const float*)d_in[15];

  // f32 sums accumulate in d_out (exactly NN*HID f32); node_kernel reads a
  // node's sums strictly before writing the same node's output row.
  float* sums = (float*)d_out;

  // workspace layout (~26 MB, proven available)
  float*  counts  = (float*)d_ws;                      // NN
  ushort* hs_proj = (ushort*)(counts + NN);            // NN*HID bf16
  ushort* hd_proj = hs_proj + (long)NN*HID;            // NN*HID bf16
  float*  embp    = (float*)(hd_proj + (long)NN*HID);  // 256 f32
  ushort* wap     = (ushort*)(embp + 256);             // 4 ks
  ushort* wbp     = wap + 4*4096;
  ushort* w1dp    = wbp + 4*4096;                      // 1 ks
  ushort* w2p     = w1dp + 1*4096;                     // 4 ks

  hipMemsetAsync(sums, 0, (size_t)NN*HID*4, stream);
  hipMemsetAsync(counts, 0, (size_t)NN*4, stream);
  embp_kernel<<<1, 256, 0, stream>>>(emb, mw1, mb1, embp);
  pack_w_kernel<<<8,  256, 0, stream>>>(mw1,             wap,  128, 4);
  pack_w_kernel<<<8,  256, 0, stream>>>(mw1 + 128*HID,   wbp,  128, 4);
  pack_w_kernel<<<2,  256, 0, stream>>>(mw1 + 384*HID,   w1dp,  32, 1);
  pack_w_kernel<<<8,  256, 0, stream>>>(mw2,             w2p,  128, 4);
  counts_kernel<<<(NE + 255)/256, 256, 0, stream>>>(eidx, counts);
  proj_kernel<<<(NN + 63)/64, 256, 0, stream>>>(h, wap, wbp, hs_proj, hd_proj);
  edge_kernel<<<NE/64, 256, 0, stream>>>(hs_proj, hd_proj, pos, eidx, etyp,
                                         embp, mw1 + 416*HID, w1dp, w2p, mb2, sums);
  node_kernel<<<(NN + 63)/64, 256, 0, stream>>>(h, sums, counts, ntyp,
                                                uw1, ub1, uw2, ub2,
                                                lng, lnb, (float*)d_out);
}

// Round 6
// 626.683 us; speedup vs baseline: 5.1292x; 1.0022x over previous
//
#include <hip/hip_runtime.h>
#include <hip/hip_bf16.h>
#include <math.h>

#define NN   50000
#define NE   800000
#define HID  128
#define NRBF 32
#define NSCAN_BLOCKS ((NN + 255) / 256)   // 196

typedef __attribute__((ext_vector_type(8))) short short8;   // 8 bf16
typedef __attribute__((ext_vector_type(4))) float floatx4;  // MFMA acc

constexpr int TILE_N = 64;

__device__ __forceinline__ float silu_f(float x) {
  return x / (1.0f + __expf(-x));
}
__device__ __forceinline__ ushort f2bf(float f) {
  __hip_bfloat16 b = __float2bfloat16(f);
  return *reinterpret_cast<ushort*>(&b);
}
__device__ __forceinline__ float bf2f(ushort u) {
  union { uint u32; float f; } c; c.u32 = ((uint)u) << 16; return c.f;
}

// ---------- CSR build ----------
__global__ void counts_i_kernel(const int* __restrict__ edge_index, int* __restrict__ cnt) {
  const int e = blockIdx.x * blockDim.x + threadIdx.x;
  if (e < NE) atomicAdd(&cnt[edge_index[NE + e]], 1);
}

__global__ void counts_f_kernel(const int* __restrict__ cnt, float* __restrict__ cf) {
  const int i = blockIdx.x * blockDim.x + threadIdx.x;
  if (i < NN) cf[i] = (float)cnt[i];
}

// per-block inclusive scan of cnt -> incl, block totals -> bsum
__global__ void scan_a_kernel(const int* __restrict__ cnt, int* __restrict__ incl,
                              int* __restrict__ bsum) {
  __shared__ int s[256];
  const int i = blockIdx.x * 256 + threadIdx.x;
  const int v = (i < NN) ? cnt[i] : 0;
  s[threadIdx.x] = v;
  __syncthreads();
  for (int off = 1; off < 256; off <<= 1) {
    const int x = (threadIdx.x >= off) ? s[threadIdx.x - off] : 0;
    __syncthreads();
    s[threadIdx.x] += x;
    __syncthreads();
  }
  if (i < NN) incl[i] = s[threadIdx.x];
  if (threadIdx.x == 255) bsum[blockIdx.x] = s[255];
}

// single-block exclusive scan of bsum (nb <= 256) in place
__global__ void scan_b_kernel(int* __restrict__ bsum, int nb) {
  __shared__ int s[256];
  const int v = (threadIdx.x < nb) ? bsum[threadIdx.x] : 0;
  s[threadIdx.x] = v;
  __syncthreads();
  for (int off = 1; off < 256; off <<= 1) {
    const int x = (threadIdx.x >= off) ? s[threadIdx.x - off] : 0;
    __syncthreads();
    s[threadIdx.x] += x;
    __syncthreads();
  }
  bsum[threadIdx.x] = s[threadIdx.x] - v;   // exclusive
}

__global__ void scan_c_kernel(const int* __restrict__ incl, const int* __restrict__ cnt,
                              const int* __restrict__ bsumex, int* __restrict__ starts) {
  const int i = blockIdx.x * 256 + threadIdx.x;
  if (i < NN) starts[i] = incl[i] - cnt[i] + bsumex[blockIdx.x];
  if (i == 0) starts[NN] = NE;
}

__global__ void perm_kernel(const int* __restrict__ edge_index, const int* __restrict__ starts,
                            int* __restrict__ cursor, int* __restrict__ perm) {
  const int e = blockIdx.x * blockDim.x + threadIdx.x;
  if (e < NE) {
    const int d = edge_index[NE + e];
    const int pos = atomicAdd(&cursor[d], 1);
    perm[starts[d] + pos] = e;
  }
}

// ---------- weight prep ----------
// embp[2][128] = emb @ mw1[256:384] + mb1   (f32, bias folded)
__global__ void embp_kernel(const float* __restrict__ emb, const float* __restrict__ mw1,
                            const float* __restrict__ mb1, float* __restrict__ embp) {
  const int t = threadIdx.x;
  const int row = t >> 7, col = t & 127;
  float s = mb1[col];
  for (int k = 0; k < HID; ++k)
    s = fmaf(emb[row * HID + k], mw1[(256 + k) * HID + col], s);
  embp[row * HID + col] = s;
}

// Pack W [Korig x 128] f32 into bf16 MFMA B-fragment order:
// out[((kk*8 + c)*64 + lane)*8 + j] = W[kk*32 + (lane>>4)*8 + j][c*16 + (lane&15)]
__global__ void pack_w_kernel(const float* __restrict__ W, ushort* __restrict__ out,
                              int Korig, int nks) {
  const int tid = blockIdx.x * blockDim.x + threadIdx.x;
  if (tid >= nks * 8 * 64) return;
  const int l = tid & 63;
  const int c = (tid >> 6) & 7;
  const int kk = tid >> 9;
  union { ushort u[8]; uint4 v; } o;
  #pragma unroll
  for (int j = 0; j < 8; ++j) {
    const int k = kk * 32 + ((l >> 4) * 8) + j;
    const float f = (k < Korig) ? W[k * HID + c * 16 + (l & 15)] : 0.0f;
    o.u[j] = f2bf(f);
  }
  reinterpret_cast<uint4*>(out)[tid] = o.v;
}

// hs_proj = h @ mw1[0:128], hd_proj = h @ mw1[128:256]  (bf16 out)
__global__ __launch_bounds__(256, 3)
void proj_kernel(const float* __restrict__ h,
                 const ushort* __restrict__ wap, const ushort* __restrict__ wbp,
                 ushort* __restrict__ hs_proj, ushort* __restrict__ hd_proj)
{
  __shared__ __align__(16) ushort sH[64 * HID];   // 16 KB, swizzled
  char* const sHb = reinterpret_cast<char*>(sH);
  const int t  = threadIdx.x;
  const int n0 = blockIdx.x * 64;

  {  // build A tile (f32 -> bf16)
    const int e = t >> 2, c0 = (t & 3) * 32;
    const int node = n0 + e;
    const int sm = (e & 7) << 4;
    #pragma unroll
    for (int m = 0; m < 4; ++m) {
      const int c = c0 + m * 8;
      float4 f0 = make_float4(0,0,0,0), f1 = f0;
      if (node < NN) {
        f0 = *reinterpret_cast<const float4*>(h + (long)node * HID + c);
        f1 = *reinterpret_cast<const float4*>(h + (long)node * HID + c + 4);
      }
      union { ushort u[8]; uint4 v; } o;
      o.u[0]=f2bf(f0.x); o.u[1]=f2bf(f0.y); o.u[2]=f2bf(f0.z); o.u[3]=f2bf(f0.w);
      o.u[4]=f2bf(f1.x); o.u[5]=f2bf(f1.y); o.u[6]=f2bf(f1.z); o.u[7]=f2bf(f1.w);
      *reinterpret_cast<uint4*>(sHb + ((e * 256 + c * 2) ^ sm)) = o.v;
    }
  }
  __syncthreads();

  const int lane = t & 63;
  const int w    = t >> 6;
  const int rt0  = (w & 1) * 2;
  const int ct0  = (w >> 1) * 4;
  const int lrow = lane & 15;
  const int lk16 = (lane >> 4) * 16;
  const int rowA0 = rt0 * 16 + lrow, rowA1 = rowA0 + 16;
  const int smA0 = (rowA0 & 7) << 4, smA1 = (rowA1 & 7) << 4;

  floatx4 accA[2][4] = {}, accB[2][4] = {};
  const ushort* const baseA = wap + ((size_t)ct0 * 64 + lane) * 8;
  const ushort* const baseB = wbp + ((size_t)ct0 * 64 + lane) * 8;
  #pragma unroll
  for (int kk = 0; kk < 4; ++kk) {
    short8 afr[2];
    afr[0] = *reinterpret_cast<const short8*>(sHb + rowA0 * 256 + ((kk*64 + lk16) ^ smA0));
    afr[1] = *reinterpret_cast<const short8*>(sHb + rowA1 * 256 + ((kk*64 + lk16) ^ smA1));
    #pragma unroll
    for (int j = 0; j < 4; ++j) {
      const short8 bA = *reinterpret_cast<const short8*>(baseA + kk * 4096 + j * 512);
      const short8 bB = *reinterpret_cast<const short8*>(baseB + kk * 4096 + j * 512);
      #pragma unroll
      for (int i = 0; i < 2; ++i) {
        accA[i][j] = __builtin_amdgcn_mfma_f32_16x16x32_bf16(afr[i], bA, accA[i][j], 0, 0, 0);
        accB[i][j] = __builtin_amdgcn_mfma_f32_16x16x32_bf16(afr[i], bB, accB[i][j], 0, 0, 0);
      }
    }
  }
  #pragma unroll
  for (int i = 0; i < 2; ++i)
    #pragma unroll
    for (int r = 0; r < 4; ++r) {
      const int row = (rt0 + i) * 16 + (lane >> 4) * 4 + r;
      const int node = n0 + row;
      if (node < NN) {
        #pragma unroll
        for (int j = 0; j < 4; ++j) {
          const int col = (ct0 + j) * 16 + lrow;
          hs_proj[(long)node * HID + col] = f2bf(accA[i][j][r]);
          hd_proj[(long)node * HID + col] = f2bf(accB[i][j][r]);
        }
      }
    }
}

// 64 CSR-ordered edges/block: pre-sum gather + K=32 rbf MFMA + silu + K=128 GEMM2
// + LDS message buffer + dst-segment reduction (few atomics).
__global__ __launch_bounds__(256, 3)
void edge_kernel(const ushort* __restrict__ hs_proj, const ushort* __restrict__ hd_proj,
                 const float* __restrict__ pos,
                 const int* __restrict__ edge_index, const int* __restrict__ edge_type,
                 const int* __restrict__ perm,
                 const float* __restrict__ embp, const float* __restrict__ w416,
                 const ushort* __restrict__ w1dp, const ushort* __restrict__ w2p,
                 const float* __restrict__ mb2,
                 float* sums)
{
  __shared__ __align__(16) uint4  sRbf[64 * 4];      // 4 KB
  __shared__ __align__(16) float  sPre[64 * HID];    // 32 KB, swizzled; reused for messages
  __shared__ __align__(16) ushort sX[64 * HID];      // 16 KB, swizzled
  __shared__ int   sSrc[64], sDst[64], sEt[64];
  __shared__ float sDist[64];
  char* const sPreB = reinterpret_cast<char*>(sPre);
  char* const sXb   = reinterpret_cast<char*>(sX);

  const int t  = threadIdx.x;
  const int e0 = blockIdx.x * 64;

  if (t < 64) {
    const int p = perm[e0 + t];
    const int s = edge_index[p];
    const int d = edge_index[NE + p];
    sSrc[t] = s; sDst[t] = d; sEt[t] = edge_type[p];
    const float dx = pos[3*s]   - pos[3*d];
    const float dy = pos[3*s+1] - pos[3*d+1];
    const float dz = pos[3*s+2] - pos[3*d+2];
    sDist[t] = sqrtf(dx*dx + dy*dy + dz*dz);
  }
  __syncthreads();

  {  // pre-sum + rbf build
    const int e = t >> 2, q = t & 3;
    const int c0 = q * 32;
    const int src = sSrc[e], et = sEt[e];
    const float dist = sDist[e];
    const ushort* const hsr = hs_proj + (long)src * HID;
    const ushort* const hdr = hd_proj + (long)sDst[e] * HID;
    const float*  const ep  = embp + et * HID;
    const int sm = (e & 7) << 4;
    #pragma unroll
    for (int m = 0; m < 4; ++m) {
      const int c = c0 + m * 8;
      const uint4 a = *reinterpret_cast<const uint4*>(hsr + c);
      const uint4 b = *reinterpret_cast<const uint4*>(hdr + c);
      const float4 ef0 = *reinterpret_cast<const float4*>(ep + c);
      const float4 ef1 = *reinterpret_cast<const float4*>(ep + c + 4);
      const float4 w0  = *reinterpret_cast<const float4*>(w416 + c);
      const float4 w1  = *reinterpret_cast<const float4*>(w416 + c + 4);
      const ushort* au = reinterpret_cast<const ushort*>(&a);
      const ushort* bu = reinterpret_cast<const ushort*>(&b);
      float4 o0, o1;
      o0.x = bf2f(au[0]) + bf2f(bu[0]) + ef0.x + dist * w0.x;
      o0.y = bf2f(au[1]) + bf2f(bu[1]) + ef0.y + dist * w0.y;
      o0.z = bf2f(au[2]) + bf2f(bu[2]) + ef0.z + dist * w0.z;
      o0.w = bf2f(au[3]) + bf2f(bu[3]) + ef0.w + dist * w0.w;
      o1.x = bf2f(au[4]) + bf2f(bu[4]) + ef1.x + dist * w1.x;
      o1.y = bf2f(au[5]) + bf2f(bu[5]) + ef1.y + dist * w1.y;
      o1.z = bf2f(au[6]) + bf2f(bu[6]) + ef1.z + dist * w1.z;
      o1.w = bf2f(au[7]) + bf2f(bu[7]) + ef1.w + dist * w1.w;
      const int byte0 = e * 512 + c * 4;
      *reinterpret_cast<float4*>(sPreB + (byte0 ^ sm))        = o0;
      *reinterpret_cast<float4*>(sPreB + ((byte0 + 16) ^ sm)) = o1;
    }
    // rbf [64][32] bf16, frag-chunked [row][kg] with kg ^ (row&3)
    const float step  = 6.0f / 31.0f;
    const float gamma = 1.0f / (step * step);
    const int r0 = q * 8;
    union { ushort u[8]; uint4 v; } o;
    #pragma unroll
    for (int j = 0; j < 8; ++j) {
      const float dd = dist - step * (float)(r0 + j);
      o.u[j] = f2bf(__expf(-gamma * dd * dd));
    }
    sRbf[e * 4 + (q ^ (e & 3))] = o.v;
  }
  __syncthreads();

  const int lane = t & 63;
  const int w    = t >> 6;
  const int rt0  = (w & 1) * 2;
  const int ct0  = (w >> 1) * 4;
  const int lrow = lane & 15;
  const int lk16 = (lane >> 4) * 16;
  const int rowA0 = rt0 * 16 + lrow, rowA1 = rowA0 + 16;

  // ---- layer 1: acc = pre (C-layout reads) + rbf @ W1d (one k-step) ----
  floatx4 acc[2][4];
  #pragma unroll
  for (int i = 0; i < 2; ++i)
    #pragma unroll
    for (int r = 0; r < 4; ++r) {
      const int row = (rt0 + i) * 16 + (lane >> 4) * 4 + r;
      const int sm = (row & 7) << 4;
      #pragma unroll
      for (int j = 0; j < 4; ++j) {
        const int col = (ct0 + j) * 16 + lrow;
        acc[i][j][r] = *reinterpret_cast<const float*>(sPreB + ((row * 512 + col * 4) ^ sm));
      }
    }
  {
    short8 a0 = *reinterpret_cast<const short8*>(&sRbf[rowA0 * 4 + ((lane >> 4) ^ (rowA0 & 3))]);
    short8 a1 = *reinterpret_cast<const short8*>(&sRbf[rowA1 * 4 + ((lane >> 4) ^ (rowA1 & 3))]);
    #pragma unroll
    for (int j = 0; j < 4; ++j) {
      const short8 b = *reinterpret_cast<const short8*>(w1dp + ((size_t)(ct0 + j) * 64 + lane) * 8);
      acc[0][j] = __builtin_amdgcn_mfma_f32_16x16x32_bf16(a0, b, acc[0][j], 0, 0, 0);
      acc[1][j] = __builtin_amdgcn_mfma_f32_16x16x32_bf16(a1, b, acc[1][j], 0, 0, 0);
    }
  }
  // silu -> sX (bf16, swizzled). mb1 already folded into embp.
  #pragma unroll
  for (int i = 0; i < 2; ++i)
    #pragma unroll
    for (int r = 0; r < 4; ++r) {
      const int row = (rt0 + i) * 16 + (lane >> 4) * 4 + r;
      const int sm = (row & 7) << 4;
      #pragma unroll
      for (int j = 0; j < 4; ++j) {
        const int col = (ct0 + j) * 16 + lrow;
        *reinterpret_cast<ushort*>(sXb + row * 256 + ((col * 2) ^ sm)) = f2bf(silu_f(acc[i][j][r]));
      }
    }
  __syncthreads();

  // ---- layer 2: [64 x 128] @ [128 x 128] ----
  floatx4 acc2[2][4] = {};
  {
    const int smA0 = (rowA0 & 7) << 4, smA1 = (rowA1 & 7) << 4;
    const ushort* const bbase = w2p + ((size_t)ct0 * 64 + lane) * 8;
    #pragma unroll 2
    for (int kk = 0; kk < 4; ++kk) {
      short8 bfr[4];
      #pragma unroll
      for (int j = 0; j < 4; ++j)
        bfr[j] = *reinterpret_cast<const short8*>(bbase + kk * 4096 + j * 512);
      short8 afr[2];
      afr[0] = *reinterpret_cast<const short8*>(sXb + rowA0 * 256 + ((kk*64 + lk16) ^ smA0));
      afr[1] = *reinterpret_cast<const short8*>(sXb + rowA1 * 256 + ((kk*64 + lk16) ^ smA1));
      #pragma unroll
      for (int i = 0; i < 2; ++i)
        #pragma unroll
        for (int j = 0; j < 4; ++j)
          acc2[i][j] = __builtin_amdgcn_mfma_f32_16x16x32_bf16(afr[i], bfr[j], acc2[i][j], 0, 0, 0);
    }
  }

  // epilogue: bias + silu -> messages into sPre (f32, swizzled rows)
  {
    float b2v[4];
    #pragma unroll
    for (int j = 0; j < 4; ++j) b2v[j] = mb2[(ct0 + j) * 16 + lrow];
    #pragma unroll
    for (int i = 0; i < 2; ++i)
      #pragma unroll
      for (int r = 0; r < 4; ++r) {
        const int row = (rt0 + i) * 16 + (lane >> 4) * 4 + r;
        const int sm = (row & 7) << 4;
        #pragma unroll
        for (int j = 0; j < 4; ++j) {
          const int col = (ct0 + j) * 16 + lrow;
          *reinterpret_cast<float*>(sPreB + ((row * 512 + col * 4) ^ sm)) =
              silu_f(acc2[i][j][r] + b2v[j]);
        }
      }
  }
  __syncthreads();

  // dst-segment reduction: rows are CSR-sorted by dst -> accumulate runs,
  // one atomicAdd per (segment, column). Branches are wave-uniform.
  {
    const int half = t >> 7;          // waves 0,1 -> rows 0..31; waves 2,3 -> 32..63
    const int c    = t & 127;
    const int r0   = half * 32;
    int cur = sDst[r0];
    float accv = 0.0f;
    for (int r = r0; r < r0 + 32; ++r) {
      const int d = sDst[r];
      const float mv = *reinterpret_cast<const float*>(
          sPreB + ((r * 512 + c * 4) ^ ((r & 7) << 4)));
      if (d != cur) {
        atomicAdd(&sums[(long)cur * HID + c], accv);
        accv = 0.0f;
        cur = d;
      }
      accv += mv;
    }
    atomicAdd(&sums[(long)cur * HID + c], accv);
  }
}

// R5-proven f32 VALU node kernel: node MLP + residual + LayerNorm + ligand mask.
// NOTE: sums aliases out (d_out) — no __restrict__ on either.
__global__ __launch_bounds__(256, 1)
void node_kernel(const float* __restrict__ h,
                 const float* sums, const float* __restrict__ counts,
                 const int* __restrict__ node_type,
                 const float* __restrict__ uw1, const float* __restrict__ ub1,
                 const float* __restrict__ uw2, const float* __restrict__ ub2,
                 const float* __restrict__ ln_g, const float* __restrict__ ln_b,
                 float* out)
{
  __shared__ float sIn[TILE_N * 256];   // 64 KB: [h, agg]
  __shared__ float sU[TILE_N * HID];    // 32 KB
  __shared__ float sMu[TILE_N];
  __shared__ float sRs[TILE_N];

  const int t  = threadIdx.x;
  const int n0 = blockIdx.x * TILE_N;

  for (int idx = t; idx < TILE_N*HID; idx += 256) {
    const int n = idx >> 7, c = idx & (HID-1);
    const int node = n0 + n;
    float hv = 0.f, av = 0.f;
    if (node < NN) {
      hv = h[(long)node*HID + c];
      av = sums[(long)node*HID + c] / fmaxf(counts[node], 1.0f);
    }
    sIn[n*256 + c]       = hv;
    sIn[n*256 + HID + c] = av;
  }
  __syncthreads();

  const int tx = t & 31;
  const int ty = t >> 5;

  const float* wp = uw1 + tx*4;
  float4 acc[8];
  #pragma unroll
  for (int i = 0; i < 8; ++i) acc[i] = make_float4(0.f,0.f,0.f,0.f);
  for (int k = 0; k < 2*HID; ++k) {
    const float4 w = *reinterpret_cast<const float4*>(wp + (long)k*HID);
    #pragma unroll
    for (int i = 0; i < 8; ++i) {
      const float a = sIn[(ty*8+i)*256 + k];
      acc[i].x = fmaf(a, w.x, acc[i].x);
      acc[i].y = fmaf(a, w.y, acc[i].y);
      acc[i].z = fmaf(a, w.z, acc[i].z);
      acc[i].w = fmaf(a, w.w, acc[i].w);
    }
  }
  const float4 b1 = *reinterpret_cast<const float4*>(ub1 + tx*4);
  #pragma unroll
  for (int i = 0; i < 8; ++i) {
    const int e = ty*8 + i;
    float4 v = acc[i];
    v.x = silu_f(v.x + b1.x); v.y = silu_f(v.y + b1.y);
    v.z = silu_f(v.z + b1.z); v.w = silu_f(v.w + b1.w);
    *reinterpret_cast<float4*>(&sU[e*HID + tx*4]) = v;
  }
  __syncthreads();

  const float* wp2 = uw2 + tx*4;
  float4 acc2[8];
  #pragma unroll
  for (int i = 0; i < 8; ++i) acc2[i] = make_float4(0.f,0.f,0.f,0.f);
  for (int k = 0; k < HID; ++k) {
    const float4 w = *reinterpret_cast<const float4*>(wp2 + (long)k*HID);
    #pragma unroll
    for (int i = 0; i < 8; ++i) {
      const float a = sU[(ty*8+i)*HID + k];
      acc2[i].x = fmaf(a, w.x, acc2[i].x);
      acc2[i].y = fmaf(a, w.y, acc2[i].y);
      acc2[i].z = fmaf(a, w.z, acc2[i].z);
      acc2[i].w = fmaf(a, w.w, acc2[i].w);
    }
  }
  __syncthreads();

  const float4 b2 = *reinterpret_cast<const float4*>(ub2 + tx*4);
  #pragma unroll
  for (int i = 0; i < 8; ++i) {
    const int e = ty*8 + i;
    float4 v = acc2[i];
    v.x = sIn[e*256 + tx*4+0] + v.x + b2.x;
    v.y = sIn[e*256 + tx*4+1] + v.y + b2.y;
    v.z = sIn[e*256 + tx*4+2] + v.z + b2.z;
    v.w = sIn[e*256 + tx*4+3] + v.w + b2.w;
    *reinterpret_cast<float4*>(&sU[e*HID + tx*4]) = v;
  }
  __syncthreads();

  {
    const int n = t >> 2, q = t & 3;
    float sm = 0.f, sq = 0.f;
    #pragma unroll 8
    for (int i = 0; i < 32; ++i) {
      const float v = sU[n*HID + q*32 + i];
      sm += v; sq += v*v;
    }
    sm += __shfl_xor(sm, 1); sq += __shfl_xor(sq, 1);
    sm += __shfl_xor(sm, 2); sq += __shfl_xor(sq, 2);
    const float mu  = sm * (1.0f/HID);
    float var = sq * (1.0f/HID) - mu*mu;
    var = fmaxf(var, 0.0f);
    if (q == 0) { sMu[n] = mu; sRs[n] = rsqrtf(var + 1e-5f); }
  }
  __syncthreads();

  for (int idx = t; idx < TILE_N*HID; idx += 256) {
    const int n = idx >> 7, c = idx & (HID-1);
    const int node = n0 + n;
    if (node >= NN) continue;
    const float xv = sU[n*HID + c];
    const float normed = (xv - sMu[n]) * sRs[n] * ln_g[c] + ln_b[c];
    const float hv = sIn[n*256 + c];
    out[(long)node*HID + c] = (node_type[node] == 0) ? normed : hv;
  }
}

extern "C" void kernel_launch(void* const* d_in, const int* in_sizes, int n_in,
                              void* d_out, int out_size, void* d_ws, size_t ws_size,
                              hipStream_t stream)
{
  const float* h    = (const float*)d_in[0];
  const float* pos  = (const float*)d_in[1];
  const int*   eidx = (const int*)  d_in[2];
  const int*   etyp = (const int*)  d_in[3];
  const int*   ntyp = (const int*)  d_in[4];
  const float* emb  = (const float*)d_in[5];
  const float* mw1  = (const float*)d_in[6];
  const float* mb1  = (const float*)d_in[7];
  const float* mw2  = (const float*)d_in[8];
  const float* mb2  = (const float*)d_in[9];
  const float* uw1  = (const float*)d_in[10];
  const float* ub1  = (const float*)d_in[11];
  const float* uw2  = (const float*)d_in[12];
  const float* ub2  = (const float*)d_in[13];
  const float* lng  = (const float*)d_in[14];
  const float* lnb  = (const float*)d_in[15];

  // f32 sums accumulate in d_out (exactly NN*HID f32); node_kernel reads a
  // node's sums strictly before writing the same node's output row.
  float* sums = (float*)d_out;

  // workspace layout (~30 MB)
  float*  counts_f = (float*)d_ws;                      // NN f32
  ushort* hs_proj  = (ushort*)(counts_f + NN);          // NN*HID bf16
  ushort* hd_proj  = hs_proj + (long)NN*HID;            // NN*HID bf16
  float*  embp     = (float*)(hd_proj + (long)NN*HID);  // 256 f32
  ushort* wap      = (ushort*)(embp + 256);             // 4 ks
  ushort* wbp      = wap + 4*4096;
  ushort* w1dp     = wbp + 4*4096;                      // 1 ks
  ushort* w2p      = w1dp + 1*4096;                     // 4 ks
  int*    cnt_i    = (int*)(w2p + 4*4096);              // NN
  int*    incl     = cnt_i + NN;                        // NN
  int*    starts   = incl + NN;                         // NN+1
  int*    bsum     = starts + NN + 1;                   // 256
  int*    cursor   = bsum + 256;                        // NN
  int*    perm     = cursor + NN;                       // NE

  hipMemsetAsync(sums, 0, (size_t)NN*HID*4, stream);
  hipMemsetAsync(cnt_i, 0, (size_t)NN*4, stream);
  hipMemsetAsync(cursor, 0, (size_t)NN*4, stream);

  // CSR build
  counts_i_kernel<<<(NE + 255)/256, 256, 0, stream>>>(eidx, cnt_i);
  scan_a_kernel<<<NSCAN_BLOCKS, 256, 0, stream>>>(cnt_i, incl, bsum);
  scan_b_kernel<<<1, 256, 0, stream>>>(bsum, NSCAN_BLOCKS);
  scan_c_kernel<<<NSCAN_BLOCKS, 256, 0, stream>>>(incl, cnt_i, bsum, starts);
  counts_f_kernel<<<NSCAN_BLOCKS, 256, 0, stream>>>(cnt_i, counts_f);
  perm_kernel<<<(NE + 255)/256, 256, 0, stream>>>(eidx, starts, cursor, perm);

  // weight prep
  embp_kernel<<<1, 256, 0, stream>>>(emb, mw1, mb1, embp);
  pack_w_kernel<<<8,  256, 0, stream>>>(mw1,             wap,  128, 4);
  pack_w_kernel<<<8,  256, 0, stream>>>(mw1 + 128*HID,   wbp,  128, 4);
  pack_w_kernel<<<2,  256, 0, stream>>>(mw1 + 384*HID,   w1dp,  32, 1);
  pack_w_kernel<<<8,  256, 0, stream>>>(mw2,             w2p,  128, 4);

  proj_kernel<<<(NN + 63)/64, 256, 0, stream>>>(h, wap, wbp, hs_proj, hd_proj);
  edge_kernel<<<NE/64, 256, 0, stream>>>(hs_proj, hd_proj, pos, eidx, etyp, perm,
                                         embp, mw1 + 416*HID, w1dp, w2p, mb2, sums);
  node_kernel<<<(NN + 63)/64, 256, 0, stream>>>(h, sums, counts_f, ntyp,
                                                uw1, ub1, uw2, ub2,
                                                lng, lnb, (float*)d_out);
}

// Round 7
// 447.532 us; speedup vs baseline: 7.1825x; 1.4003x over previous
//
#include <hip/hip_runtime.h>
#include <hip/hip_bf16.h>
#include <math.h>

#define NN   50000
#define NE   800000
#define HID  128
#define NRBF 32
#define NSCAN_BLOCKS ((NN + 255) / 256)   // 196

typedef __attribute__((ext_vector_type(8))) short short8;   // 8 bf16
typedef __attribute__((ext_vector_type(4))) float floatx4;  // MFMA acc

constexpr int TILE_N = 64;

__device__ __forceinline__ float silu_f(float x) {
  return x / (1.0f + __expf(-x));
}
__device__ __forceinline__ ushort f2bf(float f) {
  __hip_bfloat16 b = __float2bfloat16(f);
  return *reinterpret_cast<ushort*>(&b);
}
__device__ __forceinline__ float bf2f(ushort u) {
  union { uint u32; float f; } c; c.u32 = ((uint)u) << 16; return c.f;
}

// ---------- CSR build ----------
__global__ void counts_i_kernel(const int* __restrict__ edge_index, int* __restrict__ cnt) {
  const int e = blockIdx.x * blockDim.x + threadIdx.x;
  if (e < NE) atomicAdd(&cnt[edge_index[NE + e]], 1);
}

// per-block inclusive scan of cnt -> incl, block totals -> bsum
__global__ void scan_a_kernel(const int* __restrict__ cnt, int* __restrict__ incl,
                              int* __restrict__ bsum) {
  __shared__ int s[256];
  const int i = blockIdx.x * 256 + threadIdx.x;
  const int v = (i < NN) ? cnt[i] : 0;
  s[threadIdx.x] = v;
  __syncthreads();
  for (int off = 1; off < 256; off <<= 1) {
    const int x = (threadIdx.x >= off) ? s[threadIdx.x - off] : 0;
    __syncthreads();
    s[threadIdx.x] += x;
    __syncthreads();
  }
  if (i < NN) incl[i] = s[threadIdx.x];
  if (threadIdx.x == 255) bsum[blockIdx.x] = s[255];
}

// single-block exclusive scan of bsum (nb <= 256) in place
__global__ void scan_b_kernel(int* __restrict__ bsum, int nb) {
  __shared__ int s[256];
  const int v = (threadIdx.x < nb) ? bsum[threadIdx.x] : 0;
  s[threadIdx.x] = v;
  __syncthreads();
  for (int off = 1; off < 256; off <<= 1) {
    const int x = (threadIdx.x >= off) ? s[threadIdx.x - off] : 0;
    __syncthreads();
    s[threadIdx.x] += x;
    __syncthreads();
  }
  bsum[threadIdx.x] = s[threadIdx.x] - v;   // exclusive
}

// incl -> starts (in place) + float counts
__global__ void scan_c_kernel(int* __restrict__ incl, const int* __restrict__ cnt,
                              const int* __restrict__ bsumex, float* __restrict__ cf) {
  const int i = blockIdx.x * 256 + threadIdx.x;
  if (i < NN) {
    const int c = cnt[i];
    incl[i] = incl[i] - c + bsumex[blockIdx.x];  // exclusive start
    cf[i] = (float)c;
  }
}

// build CSR-ordered edge records {src | et<<24, dst}
__global__ void perm_kernel(const int* __restrict__ edge_index, const int* __restrict__ edge_type,
                            const int* __restrict__ starts,
                            int* __restrict__ cursor, int2* __restrict__ rec) {
  const int e = blockIdx.x * blockDim.x + threadIdx.x;
  if (e < NE) {
    const int s  = edge_index[e];
    const int d  = edge_index[NE + e];
    const int et = edge_type[e];
    const int pos = atomicAdd(&cursor[d], 1);
    rec[starts[d] + pos] = make_int2(s | (et << 24), d);
  }
}

// ---------- weight prep ----------
// embp[2][128] = emb @ mw1[256:384] + mb1   (f32, bias folded)
__global__ void embp_kernel(const float* __restrict__ emb, const float* __restrict__ mw1,
                            const float* __restrict__ mb1, float* __restrict__ embp) {
  const int t = threadIdx.x;
  const int row = t >> 7, col = t & 127;
  float s = mb1[col];
  #pragma unroll 4
  for (int k = 0; k < HID; ++k)
    s = fmaf(emb[row * HID + k], mw1[(256 + k) * HID + col], s);
  embp[row * HID + col] = s;
}

// Pack W [Korig x 128] f32 into bf16 MFMA B-fragment order:
// out[((kk*8 + c)*64 + lane)*8 + j] = W[kk*32 + (lane>>4)*8 + j][c*16 + (lane&15)]
__global__ void pack_w_kernel(const float* __restrict__ W, ushort* __restrict__ out,
                              int Korig, int nks) {
  const int tid = blockIdx.x * blockDim.x + threadIdx.x;
  if (tid >= nks * 8 * 64) return;
  const int l = tid & 63;
  const int c = (tid >> 6) & 7;
  const int kk = tid >> 9;
  union { ushort u[8]; uint4 v; } o;
  #pragma unroll
  for (int j = 0; j < 8; ++j) {
    const int k = kk * 32 + ((l >> 4) * 8) + j;
    const float f = (k < Korig) ? W[k * HID + c * 16 + (l & 15)] : 0.0f;
    o.u[j] = f2bf(f);
  }
  reinterpret_cast<uint4*>(out)[tid] = o.v;
}

// hs_proj = h @ mw1[0:128], hd_proj = h @ mw1[128:256]  (bf16 out)
__global__ __launch_bounds__(256, 3)
void proj_kernel(const float* __restrict__ h,
                 const ushort* __restrict__ wap, const ushort* __restrict__ wbp,
                 ushort* __restrict__ hs_proj, ushort* __restrict__ hd_proj)
{
  __shared__ __align__(16) ushort sH[64 * HID];   // 16 KB, swizzled
  char* const sHb = reinterpret_cast<char*>(sH);
  const int t  = threadIdx.x;
  const int n0 = blockIdx.x * 64;

  {  // build A tile (f32 -> bf16)
    const int e = t >> 2, c0 = (t & 3) * 32;
    const int node = n0 + e;
    const int sm = (e & 7) << 4;
    #pragma unroll
    for (int m = 0; m < 4; ++m) {
      const int c = c0 + m * 8;
      float4 f0 = make_float4(0,0,0,0), f1 = f0;
      if (node < NN) {
        f0 = *reinterpret_cast<const float4*>(h + (long)node * HID + c);
        f1 = *reinterpret_cast<const float4*>(h + (long)node * HID + c + 4);
      }
      union { ushort u[8]; uint4 v; } o;
      o.u[0]=f2bf(f0.x); o.u[1]=f2bf(f0.y); o.u[2]=f2bf(f0.z); o.u[3]=f2bf(f0.w);
      o.u[4]=f2bf(f1.x); o.u[5]=f2bf(f1.y); o.u[6]=f2bf(f1.z); o.u[7]=f2bf(f1.w);
      *reinterpret_cast<uint4*>(sHb + ((e * 256 + c * 2) ^ sm)) = o.v;
    }
  }
  __syncthreads();

  const int lane = t & 63;
  const int w    = t >> 6;
  const int rt0  = (w & 1) * 2;
  const int ct0  = (w >> 1) * 4;
  const int lrow = lane & 15;
  const int lk16 = (lane >> 4) * 16;
  const int rowA0 = rt0 * 16 + lrow, rowA1 = rowA0 + 16;
  const int smA0 = (rowA0 & 7) << 4, smA1 = (rowA1 & 7) << 4;

  floatx4 accA[2][4] = {}, accB[2][4] = {};
  const ushort* const baseA = wap + ((size_t)ct0 * 64 + lane) * 8;
  const ushort* const baseB = wbp + ((size_t)ct0 * 64 + lane) * 8;
  #pragma unroll
  for (int kk = 0; kk < 4; ++kk) {
    short8 afr[2];
    afr[0] = *reinterpret_cast<const short8*>(sHb + rowA0 * 256 + ((kk*64 + lk16) ^ smA0));
    afr[1] = *reinterpret_cast<const short8*>(sHb + rowA1 * 256 + ((kk*64 + lk16) ^ smA1));
    #pragma unroll
    for (int j = 0; j < 4; ++j) {
      const short8 bA = *reinterpret_cast<const short8*>(baseA + kk * 4096 + j * 512);
      const short8 bB = *reinterpret_cast<const short8*>(baseB + kk * 4096 + j * 512);
      #pragma unroll
      for (int i = 0; i < 2; ++i) {
        accA[i][j] = __builtin_amdgcn_mfma_f32_16x16x32_bf16(afr[i], bA, accA[i][j], 0, 0, 0);
        accB[i][j] = __builtin_amdgcn_mfma_f32_16x16x32_bf16(afr[i], bB, accB[i][j], 0, 0, 0);
      }
    }
  }
  #pragma unroll
  for (int i = 0; i < 2; ++i)
    #pragma unroll
    for (int r = 0; r < 4; ++r) {
      const int row = (rt0 + i) * 16 + (lane >> 4) * 4 + r;
      const int node = n0 + row;
      if (node < NN) {
        #pragma unroll
        for (int j = 0; j < 4; ++j) {
          const int col = (ct0 + j) * 16 + lrow;
          hs_proj[(long)node * HID + col] = f2bf(accA[i][j][r]);
          hd_proj[(long)node * HID + col] = f2bf(accB[i][j][r]);
        }
      }
    }
}

// 64 CSR-ordered edges/block. LDS union: PRE(f32 32K) -> X(bf16 16K) -> MSG(f32 32K).
__global__ __launch_bounds__(256, 4)
void edge_kernel(const ushort* __restrict__ hs_proj, const ushort* __restrict__ hd_proj,
                 const float* __restrict__ pos, const int2* __restrict__ rec,
                 const float* __restrict__ embp, const float* __restrict__ w416,
                 const ushort* __restrict__ w1dp, const ushort* __restrict__ w2p,
                 const float* __restrict__ mb2,
                 float* sums)
{
  __shared__ __align__(16) uint4 sRbf[64 * 4];    // 4 KB
  __shared__ __align__(16) char  sBuf[64 * 512];  // 32 KB union
  __shared__ int sDst[64];

  const int t  = threadIdx.x;
  const int e0 = blockIdx.x * 64;
  const int e  = t >> 2, q = t & 3;

  // phase0: per-thread edge record (coalesced, 4-lane redundant)
  const int2 rc = rec[e0 + e];
  const int src = rc.x & 0x00FFFFFF;
  const int et  = ((unsigned)rc.x) >> 24;
  const int dst = rc.y;
  if (q == 0) sDst[e] = dst;

  const float dx = pos[3*src]   - pos[3*dst];
  const float dy = pos[3*src+1] - pos[3*dst+1];
  const float dz = pos[3*src+2] - pos[3*dst+2];
  const float dist = sqrtf(dx*dx + dy*dy + dz*dz);

  // phase1: pre-sum into PRE (f32, swizzled) + rbf
  {
    const int c0 = q * 32;
    const ushort* const hsr = hs_proj + (long)src * HID;
    const ushort* const hdr = hd_proj + (long)dst * HID;
    const float*  const ep  = embp + et * HID;
    const int sm = (e & 7) << 4;
    #pragma unroll
    for (int m = 0; m < 4; ++m) {
      const int c = c0 + m * 8;
      const uint4 a = *reinterpret_cast<const uint4*>(hsr + c);
      const uint4 b = *reinterpret_cast<const uint4*>(hdr + c);
      const float4 ef0 = *reinterpret_cast<const float4*>(ep + c);
      const float4 ef1 = *reinterpret_cast<const float4*>(ep + c + 4);
      const float4 w0  = *reinterpret_cast<const float4*>(w416 + c);
      const float4 w1  = *reinterpret_cast<const float4*>(w416 + c + 4);
      const ushort* au = reinterpret_cast<const ushort*>(&a);
      const ushort* bu = reinterpret_cast<const ushort*>(&b);
      float4 o0, o1;
      o0.x = bf2f(au[0]) + bf2f(bu[0]) + ef0.x + dist * w0.x;
      o0.y = bf2f(au[1]) + bf2f(bu[1]) + ef0.y + dist * w0.y;
      o0.z = bf2f(au[2]) + bf2f(bu[2]) + ef0.z + dist * w0.z;
      o0.w = bf2f(au[3]) + bf2f(bu[3]) + ef0.w + dist * w0.w;
      o1.x = bf2f(au[4]) + bf2f(bu[4]) + ef1.x + dist * w1.x;
      o1.y = bf2f(au[5]) + bf2f(bu[5]) + ef1.y + dist * w1.y;
      o1.z = bf2f(au[6]) + bf2f(bu[6]) + ef1.z + dist * w1.z;
      o1.w = bf2f(au[7]) + bf2f(bu[7]) + ef1.w + dist * w1.w;
      const int byte0 = e * 512 + c * 4;
      *reinterpret_cast<float4*>(sBuf + (byte0 ^ sm))        = o0;
      *reinterpret_cast<float4*>(sBuf + ((byte0 + 16) ^ sm)) = o1;
    }
    const float step  = 6.0f / 31.0f;
    const float gamma = 1.0f / (step * step);
    const int r0 = q * 8;
    union { ushort u[8]; uint4 v; } o;
    #pragma unroll
    for (int j = 0; j < 8; ++j) {
      const float dd = dist - step * (float)(r0 + j);
      o.u[j] = f2bf(__expf(-gamma * dd * dd));
    }
    sRbf[e * 4 + (q ^ (e & 3))] = o.v;
  }
  __syncthreads();   // (1) PRE + rbf + sDst visible

  const int lane = t & 63;
  const int w    = t >> 6;
  const int rt0  = (w & 1) * 2;
  const int ct0  = (w >> 1) * 4;
  const int lrow = lane & 15;
  const int lk16 = (lane >> 4) * 16;
  const int rowA0 = rt0 * 16 + lrow, rowA1 = rowA0 + 16;
  const int smA0 = (rowA0 & 7) << 4, smA1 = (rowA1 & 7) << 4;

  // layer 1: acc = PRE (C-layout reads) + rbf @ W1d
  floatx4 acc[2][4];
  #pragma unroll
  for (int i = 0; i < 2; ++i)
    #pragma unroll
    for (int r = 0; r < 4; ++r) {
      const int row = (rt0 + i) * 16 + (lane >> 4) * 4 + r;
      const int sm = (row & 7) << 4;
      #pragma unroll
      for (int j = 0; j < 4; ++j) {
        const int col = (ct0 + j) * 16 + lrow;
        acc[i][j][r] = *reinterpret_cast<const float*>(sBuf + ((row * 512 + col * 4) ^ sm));
      }
    }
  {
    short8 a0 = *reinterpret_cast<const short8*>(&sRbf[rowA0 * 4 + ((lane >> 4) ^ (rowA0 & 3))]);
    short8 a1 = *reinterpret_cast<const short8*>(&sRbf[rowA1 * 4 + ((lane >> 4) ^ (rowA1 & 3))]);
    #pragma unroll
    for (int j = 0; j < 4; ++j) {
      const short8 b = *reinterpret_cast<const short8*>(w1dp + ((size_t)(ct0 + j) * 64 + lane) * 8);
      acc[0][j] = __builtin_amdgcn_mfma_f32_16x16x32_bf16(a0, b, acc[0][j], 0, 0, 0);
      acc[1][j] = __builtin_amdgcn_mfma_f32_16x16x32_bf16(a1, b, acc[1][j], 0, 0, 0);
    }
  }
  __syncthreads();   // (2) all PRE reads done; region reusable

  // silu -> X (bf16, swizzled) into sBuf[0:16K]
  #pragma unroll
  for (int i = 0; i < 2; ++i)
    #pragma unroll
    for (int r = 0; r < 4; ++r) {
      const int row = (rt0 + i) * 16 + (lane >> 4) * 4 + r;
      const int sm = (row & 7) << 4;
      #pragma unroll
      for (int j = 0; j < 4; ++j) {
        const int col = (ct0 + j) * 16 + lrow;
        *reinterpret_cast<ushort*>(sBuf + row * 256 + ((col * 2) ^ sm)) = f2bf(silu_f(acc[i][j][r]));
      }
    }
  __syncthreads();   // (3) X visible

  // layer 2: [64 x 128] @ [128 x 128]
  floatx4 acc2[2][4] = {};
  {
    const ushort* const bbase = w2p + ((size_t)ct0 * 64 + lane) * 8;
    #pragma unroll 2
    for (int kk = 0; kk < 4; ++kk) {
      short8 bfr[4];
      #pragma unroll
      for (int j = 0; j < 4; ++j)
        bfr[j] = *reinterpret_cast<const short8*>(bbase + kk * 4096 + j * 512);
      short8 afr[2];
      afr[0] = *reinterpret_cast<const short8*>(sBuf + rowA0 * 256 + ((kk*64 + lk16) ^ smA0));
      afr[1] = *reinterpret_cast<const short8*>(sBuf + rowA1 * 256 + ((kk*64 + lk16) ^ smA1));
      #pragma unroll
      for (int i = 0; i < 2; ++i)
        #pragma unroll
        for (int j = 0; j < 4; ++j)
          acc2[i][j] = __builtin_amdgcn_mfma_f32_16x16x32_bf16(afr[i], bfr[j], acc2[i][j], 0, 0, 0);
    }
  }
  __syncthreads();   // (4) all X reads done; region reusable

  // epilogue: bias + silu -> MSG (f32, swizzled)
  {
    float b2v[4];
    #pragma unroll
    for (int j = 0; j < 4; ++j) b2v[j] = mb2[(ct0 + j) * 16 + lrow];
    #pragma unroll
    for (int i = 0; i < 2; ++i)
      #pragma unroll
      for (int r = 0; r < 4; ++r) {
        const int row = (rt0 + i) * 16 + (lane >> 4) * 4 + r;
        const int sm = (row & 7) << 4;
        #pragma unroll
        for (int j = 0; j < 4; ++j) {
          const int col = (ct0 + j) * 16 + lrow;
          *reinterpret_cast<float*>(sBuf + ((row * 512 + col * 4) ^ sm)) =
              silu_f(acc2[i][j][r] + b2v[j]);
        }
      }
  }
  __syncthreads();   // (5) MSG visible

  // dst-segment reduction: one atomicAdd per (segment, column)
  {
    const int half = t >> 7;
    const int c    = t & 127;
    const int r0   = half * 32;
    int cur = sDst[r0];
    float accv = 0.0f;
    for (int r = r0; r < r0 + 32; ++r) {
      const int d = sDst[r];
      const float mv = *reinterpret_cast<const float*>(
          sBuf + ((r * 512 + c * 4) ^ ((r & 7) << 4)));
      if (d != cur) {
        atomicAdd(&sums[(long)cur * HID + c], accv);
        accv = 0.0f;
        cur = d;
      }
      accv += mv;
    }
    atomicAdd(&sums[(long)cur * HID + c], accv);
  }
}

// f32 VALU node kernel (R5-proven math), LDS-compacted: sU aliases sIn agg half.
// NOTE: sums aliases out (d_out) — no __restrict__ on either.
__global__ __launch_bounds__(256, 2)
void node_kernel(const float* __restrict__ h,
                 const float* sums, const float* __restrict__ counts,
                 const int* __restrict__ node_type,
                 const float* __restrict__ uw1, const float* __restrict__ ub1,
                 const float* __restrict__ uw2, const float* __restrict__ ub2,
                 const float* __restrict__ ln_g, const float* __restrict__ ln_b,
                 float* out)
{
  __shared__ float sIn[TILE_N * 256];   // 64 KB: [h | agg]; agg half -> sU -> x
  __shared__ float sMu[TILE_N];
  __shared__ float sRs[TILE_N];

  const int t  = threadIdx.x;
  const int n0 = blockIdx.x * TILE_N;

  for (int idx = t; idx < TILE_N*HID; idx += 256) {
    const int n = idx >> 7, c = idx & (HID-1);
    const int node = n0 + n;
    float hv = 0.f, av = 0.f;
    if (node < NN) {
      hv = h[(long)node*HID + c];
      av = sums[(long)node*HID + c] / fmaxf(counts[node], 1.0f);
    }
    sIn[n*256 + c]       = hv;
    sIn[n*256 + HID + c] = av;
  }
  __syncthreads();

  const int tx = t & 31;
  const int ty = t >> 5;

  // GEMM1: [64 x 256] @ [256 x 128] (reads all of sIn)
  const float* wp = uw1 + tx*4;
  float4 acc[8];
  #pragma unroll
  for (int i = 0; i < 8; ++i) acc[i] = make_float4(0.f,0.f,0.f,0.f);
  for (int k = 0; k < 2*HID; ++k) {
    const float4 w = *reinterpret_cast<const float4*>(wp + (long)k*HID);
    #pragma unroll
    for (int i = 0; i < 8; ++i) {
      const float a = sIn[(ty*8+i)*256 + k];
      acc[i].x = fmaf(a, w.x, acc[i].x);
      acc[i].y = fmaf(a, w.y, acc[i].y);
      acc[i].z = fmaf(a, w.z, acc[i].z);
      acc[i].w = fmaf(a, w.w, acc[i].w);
    }
  }
  __syncthreads();   // all GEMM1 reads done before agg half reuse

  const float4 b1 = *reinterpret_cast<const float4*>(ub1 + tx*4);
  #pragma unroll
  for (int i = 0; i < 8; ++i) {
    const int e = ty*8 + i;
    float4 v = acc[i];
    v.x = silu_f(v.x + b1.x); v.y = silu_f(v.y + b1.y);
    v.z = silu_f(v.z + b1.z); v.w = silu_f(v.w + b1.w);
    *reinterpret_cast<float4*>(&sIn[e*256 + HID + tx*4]) = v;   // sU in agg half
  }
  __syncthreads();

  // GEMM2: [64 x 128] @ [128 x 128] (reads agg half)
  const float* wp2 = uw2 + tx*4;
  float4 acc2[8];
  #pragma unroll
  for (int i = 0; i < 8; ++i) acc2[i] = make_float4(0.f,0.f,0.f,0.f);
  for (int k = 0; k < HID; ++k) {
    const float4 w = *reinterpret_cast<const float4*>(wp2 + (long)k*HID);
    #pragma unroll
    for (int i = 0; i < 8; ++i) {
      const float a = sIn[(ty*8+i)*256 + HID + k];
      acc2[i].x = fmaf(a, w.x, acc2[i].x);
      acc2[i].y = fmaf(a, w.y, acc2[i].y);
      acc2[i].z = fmaf(a, w.z, acc2[i].z);
      acc2[i].w = fmaf(a, w.w, acc2[i].w);
    }
  }
  __syncthreads();   // all GEMM2 reads done

  const float4 b2 = *reinterpret_cast<const float4*>(ub2 + tx*4);
  #pragma unroll
  for (int i = 0; i < 8; ++i) {
    const int e = ty*8 + i;
    float4 v = acc2[i];
    v.x = sIn[e*256 + tx*4+0] + v.x + b2.x;   // x = h + update (h half untouched)
    v.y = sIn[e*256 + tx*4+1] + v.y + b2.y;
    v.z = sIn[e*256 + tx*4+2] + v.z + b2.z;
    v.w = sIn[e*256 + tx*4+3] + v.w + b2.w;
    *reinterpret_cast<float4*>(&sIn[e*256 + HID + tx*4]) = v;   // x in agg half
  }
  __syncthreads();

  {
    const int n = t >> 2, q = t & 3;
    float sm = 0.f, sq = 0.f;
    #pragma unroll 8
    for (int i = 0; i < 32; ++i) {
      const float v = sIn[n*256 + HID + q*32 + i];
      sm += v; sq += v*v;
    }
    sm += __shfl_xor(sm, 1); sq += __shfl_xor(sq, 1);
    sm += __shfl_xor(sm, 2); sq += __shfl_xor(sq, 2);
    const float mu  = sm * (1.0f/HID);
    float var = sq * (1.0f/HID) - mu*mu;
    var = fmaxf(var, 0.0f);
    if (q == 0) { sMu[n] = mu; sRs[n] = rsqrtf(var + 1e-5f); }
  }
  __syncthreads();

  for (int idx = t; idx < TILE_N*HID; idx += 256) {
    const int n = idx >> 7, c = idx & (HID-1);
    const int node = n0 + n;
    if (node >= NN) continue;
    const float xv = sIn[n*256 + HID + c];
    const float normed = (xv - sMu[n]) * sRs[n] * ln_g[c] + ln_b[c];
    const float hv = sIn[n*256 + c];
    out[(long)node*HID + c] = (node_type[node] == 0) ? normed : hv;
  }
}

extern "C" void kernel_launch(void* const* d_in, const int* in_sizes, int n_in,
                              void* d_out, int out_size, void* d_ws, size_t ws_size,
                              hipStream_t stream)
{
  const float* h    = (const float*)d_in[0];
  const float* pos  = (const float*)d_in[1];
  const int*   eidx = (const int*)  d_in[2];
  const int*   etyp = (const int*)  d_in[3];
  const int*   ntyp = (const int*)  d_in[4];
  const float* emb  = (const float*)d_in[5];
  const float* mw1  = (const float*)d_in[6];
  const float* mb1  = (const float*)d_in[7];
  const float* mw2  = (const float*)d_in[8];
  const float* mb2  = (const float*)d_in[9];
  const float* uw1  = (const float*)d_in[10];
  const float* ub1  = (const float*)d_in[11];
  const float* uw2  = (const float*)d_in[12];
  const float* ub2  = (const float*)d_in[13];
  const float* lng  = (const float*)d_in[14];
  const float* lnb  = (const float*)d_in[15];

  // f32 sums accumulate in d_out (exactly NN*HID f32); node_kernel reads a
  // node's sums strictly before writing the same node's output row.
  float* sums = (float*)d_out;

  // workspace layout (~33 MB)
  float*  counts_f = (float*)d_ws;                      // NN f32
  ushort* hs_proj  = (ushort*)(counts_f + NN);          // NN*HID bf16
  ushort* hd_proj  = hs_proj + (long)NN*HID;            // NN*HID bf16
  float*  embp     = (float*)(hd_proj + (long)NN*HID);  // 256 f32
  ushort* wap      = (ushort*)(embp + 256);             // 4 ks
  ushort* wbp      = wap + 4*4096;
  ushort* w1dp     = wbp + 4*4096;                      // 1 ks
  ushort* w2p      = w1dp + 1*4096;                     // 4 ks
  int*    cnt_i    = (int*)(w2p + 4*4096);              // NN
  int*    cursor   = cnt_i + NN;                        // NN (adjacent: one memset)
  int*    starts   = cursor + NN;                       // NN (incl, turned into starts)
  int*    bsum     = starts + NN;                       // 256
  int2*   rec      = (int2*)(bsum + 256);               // NE * 8B

  hipMemsetAsync(sums, 0, (size_t)NN*HID*4, stream);
  hipMemsetAsync(cnt_i, 0, (size_t)NN*2*4, stream);     // cnt_i + cursor

  // CSR build
  counts_i_kernel<<<(NE + 255)/256, 256, 0, stream>>>(eidx, cnt_i);
  scan_a_kernel<<<NSCAN_BLOCKS, 256, 0, stream>>>(cnt_i, starts, bsum);
  scan_b_kernel<<<1, 256, 0, stream>>>(bsum, NSCAN_BLOCKS);
  scan_c_kernel<<<NSCAN_BLOCKS, 256, 0, stream>>>(starts, cnt_i, bsum, counts_f);
  perm_kernel<<<(NE + 255)/256, 256, 0, stream>>>(eidx, etyp, starts, cursor, rec);

  // weight prep
  embp_kernel<<<1, 256, 0, stream>>>(emb, mw1, mb1, embp);
  pack_w_kernel<<<8,  256, 0, stream>>>(mw1,             wap,  128, 4);
  pack_w_kernel<<<8,  256, 0, stream>>>(mw1 + 128*HID,   wbp,  128, 4);
  pack_w_kernel<<<2,  256, 0, stream>>>(mw1 + 384*HID,   w1dp,  32, 1);
  pack_w_kernel<<<8,  256, 0, stream>>>(mw2,             w2p,  128, 4);

  proj_kernel<<<(NN + 63)/64, 256, 0, stream>>>(h, wap, wbp, hs_proj, hd_proj);
  edge_kernel<<<NE/64, 256, 0, stream>>>(hs_proj, hd_proj, pos, rec,
                                         embp, mw1 + 416*HID, w1dp, w2p, mb2, sums);
  node_kernel<<<(NN + 63)/64, 256, 0, stream>>>(h, sums, counts_f, ntyp,
                                                uw1, ub1, uw2, ub2,
                                                lng, lnb, (float*)d_out);
}